// Round 11
// baseline (36498.447 us; speedup 1.0000x reference)
//
#include <hip/hip_runtime.h>
#include <hip/hip_cooperative_groups.h>
#include <stdint.h>

namespace cg = cooperative_groups;

// Decoder_71880572665909 : GRU scan (T=511) + 2 x (causal self-attn + cross-attn + MLP) + linear head
// B=64, S=512, HID=1024, POSE=96, L=2.
// Round-11: perf pass on the round-10 PASS (34.4 ms, absmax 0.25).
//  - GRU: persistent cooperative kernel (1 launch, grid.sync per step; B-slices stay L2-hot),
//    gates 3-product pair-weights (B2 plane dropped; coherent 2^-18 residual integrates to ~3e-4).
//  - Phase 2: all GEMMs X3 (pair x pair); projections 5->3 products. ~201 MB workspace.

typedef __attribute__((ext_vector_type(8))) short short8;
typedef __attribute__((ext_vector_type(4))) float f32x4;

__device__ __forceinline__ uint16_t f2bf(float f) {
  uint32_t u = __float_as_uint(f);
  uint32_t r = u + 0x7FFFu + ((u >> 16) & 1u);
  return (uint16_t)(r >> 16);
}
__device__ __forceinline__ float bf2f(uint16_t h) {
  return __uint_as_float(((uint32_t)h) << 16);
}
__device__ __forceinline__ float sigm(float x) { return 1.f / (1.f + __expf(-x)); }
__device__ __forceinline__ float tanh_(float x) { return 2.f / (1.f + __expf(-2.f * x)) - 1.f; }
__device__ __forceinline__ short8 ld8(const uint16_t* p) { return *(const short8*)p; }

__device__ __forceinline__ void stage16(const void* g, void* lds_base_uniform) {
  __builtin_amdgcn_global_load_lds((const __attribute__((address_space(1))) void*)g,
                                   (__attribute__((address_space(3))) void*)lds_base_uniform, 16, 0, 0);
}
__device__ __forceinline__ void tri_store(uint16_t* p, long long o0, long long o1, long long o2, float v) {
  uint16_t hi = f2bf(v);
  float r = v - bf2f(hi);
  uint16_t mid = f2bf(r);
  p[o0] = hi; p[o1] = mid; p[o2] = f2bf(r - bf2f(mid));
}
__device__ __forceinline__ void pair_store(uint16_t* p, long long o0, long long o1, float v) {
  uint16_t hi = f2bf(v);
  p[o0] = hi; p[o1] = f2bf(v - bf2f(hi));
}

// ---------------------------------------------------------------- prep / utility kernels

__global__ __launch_bounds__(256) void k_fill(float* __restrict__ o, int n, float v) {
  int i = blockIdx.x * 256 + threadIdx.x;
  if (i < n) o[i] = v;
}

__global__ __launch_bounds__(256) void k_cp4(const float4* __restrict__ s, float4* __restrict__ d, int n4) {
  int i = blockIdx.x * 256 + threadIdx.x;
  if (i < n4) d[i] = s[i];
}

// f32 [rows][K] -> pair bf16 [rows][2K] (hi|lo)
__global__ __launch_bounds__(256) void k_split2(const float* __restrict__ s, uint16_t* __restrict__ d,
                                                int n, int K) {
  int id = blockIdx.x * 256 + threadIdx.x;
  if (id >= n) return;
  int row = id / K, k = id % K;
  long long b = (long long)row * 2 * K;
  pair_store(d, b + k, b + K + k, s[id]);
}

// f32 W [N][K] -> pair [Npad][2K]
__global__ __launch_bounds__(256) void k_fsplit(const float* __restrict__ s, uint16_t* __restrict__ d,
                                                int N, int K, int Npad) {
  int id = blockIdx.x * 256 + threadIdx.x;
  if (id >= Npad * K) return;
  int n = id / K, k = id % K;
  float w = (n < N) ? s[(long long)n * K + k] : 0.f;
  pair_store(d, (long long)n * 2 * K + k, (long long)n * 2 * K + K + k, w);
}

// x_{-1} = x0 - h0 @ tp_W^T - tp_b  (triple out; feeds step-0 gi)
__global__ __launch_bounds__(256) void k_xm1(const float* __restrict__ h, const float* __restrict__ gt,
                                             const float* __restrict__ tp_W, const float* __restrict__ tp_b,
                                             uint16_t* __restrict__ Xm1) {
  int id = blockIdx.x * 256 + threadIdx.x;
  if (id >= 64 * 96) return;
  int b = id / 96, c = id % 96;
  float s = gt[(long long)b * 512 * 96 + c] - tp_b[c];
  const float* hr = &h[(long long)b * 1024];
  const float* wr = &tp_W[(long long)c * 1024];
  for (int k = 0; k < 1024; k++) s -= hr[k] * wr[k];
  tri_store(Xm1, b * 288 + c, b * 288 + 96 + c, b * 288 + 192 + c, s);
}

// gates pack: K=1120 x N=6144 fragment order [384 tiles][35 ks][64][8], hi+mid planes
__global__ __launch_bounds__(256) void k_pack(const float* __restrict__ W_hh, const float* __restrict__ W_ih,
                                              const float* __restrict__ tp_W,
                                              uint16_t* __restrict__ B0, uint16_t* __restrict__ B1) {
  int id = blockIdx.x * 256 + threadIdx.x;
  if (id >= 384 * 35 * 64) return;
  int tile = id / 2240, rem = id % 2240;
  int ks = rem >> 6, l = rem & 63;
  int n = tile * 16 + (l & 15);
  int kb = ks * 32 + (l >> 4) * 8;
  short8 v0, v1;
#pragma unroll
  for (int i = 0; i < 8; i++) {
    int k = kb + i;
    float m = 0.f;
    if (n < 3072) {
      m = (k < 1024) ? W_hh[(long long)n * 1024 + k] : 0.f;
    } else {
      int j = n - 3072;
      if (k < 1024) {
        float s = 0.f;
        for (int q = 0; q < 96; q++) s += tp_W[q * 1024 + k] * W_ih[(long long)j * 96 + q];
        m = s;
      } else {
        m = W_ih[(long long)j * 96 + (k - 1024)];
      }
    }
    uint16_t hi = f2bf(m);
    v0[i] = (short)hi; v1[i] = (short)f2bf(m - bf2f(hi));
  }
  *(short8*)&B0[(long long)id * 8] = v0;
  *(short8*)&B1[(long long)id * 8] = v1;
}

// x-update pack: tp_W [6 tiles][32 ks][64][8], triple planes (plane stride 98304 u16)
__global__ __launch_bounds__(256) void k_packx(const float* __restrict__ tp_W, uint16_t* __restrict__ Bx) {
  int id = blockIdx.x * 256 + threadIdx.x;
  if (id >= 6 * 32 * 64) return;
  int tile = id / 2048, rem = id % 2048;
  int ks = rem >> 6, l = rem & 63;
  int c = tile * 16 + (l & 15);
  int lg = l >> 4;
  short8 v0, v1, v2;
#pragma unroll
  for (int i = 0; i < 8; i++) {
    int k = ks * 32 + lg * 8 + i;
    float w = tp_W[(long long)c * 1024 + k];
    uint16_t hi = f2bf(w);
    float r = w - bf2f(hi);
    uint16_t mid = f2bf(r);
    v0[i] = (short)hi; v1[i] = (short)mid; v2[i] = (short)f2bf(r - bf2f(mid));
  }
  *(short8*)&Bx[(long long)id * 8] = v0;
  *(short8*)&Bx[98304 + (long long)id * 8] = v1;
  *(short8*)&Bx[196608 + (long long)id * 8] = v2;
}

__global__ __launch_bounds__(256) void k_c6(const float* __restrict__ b_ih, const float* __restrict__ b_hh,
                                            const float* __restrict__ W_ih, const float* __restrict__ tp_b,
                                            float* __restrict__ c6m) {
  int n = blockIdx.x * 256 + threadIdx.x;
  if (n >= 6240) return;
  float m;
  if (n < 3072) { m = b_hh[n]; }
  else if (n < 6144) {
    int j = n - 3072;
    float s = 0.f;
    for (int q = 0; q < 96; q++) s += W_ih[(long long)j * 96 + q] * tp_b[q];
    m = b_ih[j] + s;
  } else { m = tp_b[n - 6144]; }
  c6m[n] = m;
}

__global__ __launch_bounds__(256) void k_init(const float* __restrict__ h, const float* __restrict__ gt,
                                              float* Hf, uint16_t* Hr, float* Xf, uint16_t* Xr) {
  int id = blockIdx.x * 256 + threadIdx.x;
  if (id < 65536) {
    int b = id >> 10, d = id & 1023;
    float v = h[id];
    Hf[((long long)b * 512) * 1024 + d] = v;
    tri_store(Hr, b * 3072 + d, b * 3072 + 1024 + d, b * 3072 + 2048 + d, v);
  } else {
    int r2 = id - 65536;
    if (r2 < 6144) {
      int b = r2 / 96, c = r2 % 96;
      float v = gt[(long long)b * 512 * 96 + c];
      Xf[((long long)b * 512) * 96 + c] = v;
      tri_store(Xr, b * 288 + c, b * 288 + 96 + c, b * 288 + 192 + c, v);
    }
  }
}

// ---------------------------------------------------------------- GRU step body
// grid 66: blocks 0..63 gates (16 j-cols x 6 strips), blocks 64,65 x-update (48 cols each).
__device__ __forceinline__ void gru_body(const uint16_t* __restrict__ B0, const uint16_t* __restrict__ B1,
                                         const uint16_t* __restrict__ Bx, const float* __restrict__ c6,
                                         float* Hf, uint16_t* Hr, float* Xf, uint16_t* Xr,
                                         const uint16_t* __restrict__ Xm1,
                                         int p, int blk, int tid, float* lds) {
  int w = tid >> 6, l = tid & 63, lr = l & 15, lg = l >> 4;
  const uint16_t* Hcur = Hr + (p & 1) * 196608;
  uint16_t* Hnxt = Hr + ((p + 1) & 1) * 196608;
  uint16_t* Xw = Xr + (p & 1) * 18432;
  const uint16_t* Xg = (p == 0) ? Xm1 : (Xr + ((p - 1) & 1) * 18432);

  if (blk >= 64) {  // x-update: x_p = x_{p-1} + h_p @ tpW^T + tp_b ; X6 precision
    if (p < 1) return;
    int xb = blk - 64;
    if (w < 6) {
      int tl = xb * 3 + (w >> 1);
      int kh = w & 1;
      f32x4 ac[4] = {};
      for (int ks = kh * 16; ks < kh * 16 + 16; ks++) {
        short8 a0[4], a1[4], a2[4];
        int k0 = ks * 32 + lg * 8;
#pragma unroll
        for (int rt = 0; rt < 4; rt++) {
          int hb = (rt * 16 + lr) * 3072;
          a0[rt] = ld8(&Hcur[hb + k0]);
          a1[rt] = ld8(&Hcur[hb + 1024 + k0]);
          a2[rt] = ld8(&Hcur[hb + 2048 + k0]);
        }
        long long bo = (((long long)tl * 32 + ks) * 64 + l) * 8;
        short8 b0 = ld8(&Bx[bo]);
        short8 b1 = ld8(&Bx[98304 + bo]);
        short8 b2 = ld8(&Bx[196608 + bo]);
#pragma unroll
        for (int rt = 0; rt < 4; rt++) {
          ac[rt] = __builtin_amdgcn_mfma_f32_16x16x32_bf16(a0[rt], b0, ac[rt], 0, 0, 0);
          ac[rt] = __builtin_amdgcn_mfma_f32_16x16x32_bf16(a0[rt], b1, ac[rt], 0, 0, 0);
          ac[rt] = __builtin_amdgcn_mfma_f32_16x16x32_bf16(a1[rt], b0, ac[rt], 0, 0, 0);
          ac[rt] = __builtin_amdgcn_mfma_f32_16x16x32_bf16(a1[rt], b1, ac[rt], 0, 0, 0);
          ac[rt] = __builtin_amdgcn_mfma_f32_16x16x32_bf16(a0[rt], b2, ac[rt], 0, 0, 0);
          ac[rt] = __builtin_amdgcn_mfma_f32_16x16x32_bf16(a2[rt], b0, ac[rt], 0, 0, 0);
        }
      }
#pragma unroll
      for (int rt = 0; rt < 4; rt++)
#pragma unroll
        for (int rg = 0; rg < 4; rg++)
          lds[w * 1024 + (rt * 16 + 4 * lg + rg) * 16 + lr] = ac[rt][rg];
    }
    __syncthreads();
    for (int idx = tid; idx < 3072; idx += 512) {
      int ti = idx >> 10, rem = idx & 1023;
      int row = rem >> 4, cl = rem & 15;
      float v = lds[(2 * ti) * 1024 + row * 16 + cl] + lds[(2 * ti + 1) * 1024 + row * 16 + cl];
      int c = (xb * 3 + ti) * 16 + cl;
      float xold = Xf[((long long)row * 512 + p - 1) * 96 + c];
      float xv = v + c6[6144 + c] + xold;
      Xf[((long long)row * 512 + p) * 96 + c] = xv;
      tri_store(Xw, row * 288 + c, row * 288 + 96 + c, row * 288 + 192 + c, xv);
    }
    __syncthreads();
    return;
  }

  if (p >= 511) return;
  // gates: j in [blk*16, +16); tiles s*64+blk for s=0..5. 8 waves split K(35 ks). X3 pair-weights.
  int ks0 = (w * 35) >> 3, ks1 = ((w + 1) * 35) >> 3;
  f32x4 acc[6][4] = {};
  for (int ks = ks0; ks < ks1; ks++) {
    short8 a0[4], a1[4];
    if (ks < 32) {
      int k0 = ks * 32 + lg * 8;
#pragma unroll
      for (int rt = 0; rt < 4; rt++) {
        int hb = (rt * 16 + lr) * 3072;
        a0[rt] = ld8(&Hcur[hb + k0]);
        a1[rt] = ld8(&Hcur[hb + 1024 + k0]);
      }
    } else {
      int k0 = (ks - 32) * 32 + lg * 8;
#pragma unroll
      for (int rt = 0; rt < 4; rt++) {
        int xb2 = (rt * 16 + lr) * 288;
        a0[rt] = ld8(&Xg[xb2 + k0]);
        a1[rt] = ld8(&Xg[xb2 + 96 + k0]);
      }
    }
#pragma unroll
    for (int t = 0; t < 6; t++) {
      long long bo = (((long long)(t * 64 + blk)) * 35 + ks) * 64 * 8 + (long long)l * 8;
      short8 b0 = ld8(&B0[bo]);
      short8 b1 = ld8(&B1[bo]);
#pragma unroll
      for (int rt = 0; rt < 4; rt++) {
        acc[t][rt] = __builtin_amdgcn_mfma_f32_16x16x32_bf16(a0[rt], b0, acc[t][rt], 0, 0, 0);
        acc[t][rt] = __builtin_amdgcn_mfma_f32_16x16x32_bf16(a0[rt], b1, acc[t][rt], 0, 0, 0);
        acc[t][rt] = __builtin_amdgcn_mfma_f32_16x16x32_bf16(a1[rt], b0, acc[t][rt], 0, 0, 0);
      }
    }
  }
  int slab = w & 3;
  if (w < 4) {
#pragma unroll
    for (int t = 0; t < 6; t++)
#pragma unroll
      for (int rt = 0; rt < 4; rt++)
#pragma unroll
        for (int rg = 0; rg < 4; rg++)
          lds[slab * 6144 + (rt * 16 + 4 * lg + rg) * 96 + t * 16 + lr] = acc[t][rt][rg];
  }
  __syncthreads();
  if (w >= 4) {
#pragma unroll
    for (int t = 0; t < 6; t++)
#pragma unroll
      for (int rt = 0; rt < 4; rt++)
#pragma unroll
        for (int rg = 0; rg < 4; rg++)
          lds[slab * 6144 + (rt * 16 + 4 * lg + rg) * 96 + t * 16 + lr] += acc[t][rt][rg];
  }
  __syncthreads();
  for (int idx = tid; idx < 6144; idx += 512)
    lds[idx] = lds[idx] + lds[6144 + idx] + lds[12288 + idx] + lds[18432 + idx];
  __syncthreads();
  for (int item = tid; item < 1024; item += 512) {
    int b = item >> 4, jj = item & 15;
    int j = blk * 16 + jj;
    const float* row = &lds[b * 96];
    float hr = row[jj]       + c6[j];
    float hz = row[16 + jj]  + c6[1024 + j];
    float hnn = row[32 + jj] + c6[2048 + j];
    float ir = row[48 + jj]  + c6[3072 + j];
    float iz = row[64 + jj]  + c6[4096 + j];
    float inn = row[80 + jj] + c6[5120 + j];
    float hp = Hf[((long long)b * 512 + p) * 1024 + j];
    float r = sigm(ir + hr), z = sigm(iz + hz);
    float nn = tanh_(inn + r * hnn);
    float hv = (1.f - z) * nn + z * hp;
    Hf[((long long)b * 512 + p + 1) * 1024 + j] = hv;
    tri_store(Hnxt, b * 3072 + j, b * 3072 + 1024 + j, b * 3072 + 2048 + j, hv);
  }
  __syncthreads();
}

// persistent cooperative GRU: one launch, grid.sync per step
__global__ __launch_bounds__(512) void k_gru_p(const uint16_t* __restrict__ B0, const uint16_t* __restrict__ B1,
                                               const uint16_t* __restrict__ Bx, const float* __restrict__ c6,
                                               float* Hf, uint16_t* Hr, float* Xf, uint16_t* Xr,
                                               const uint16_t* __restrict__ Xm1) {
  cg::grid_group grid = cg::this_grid();
  __shared__ float lds[4 * 6144];
  for (int p = 0; p < 512; p++) {
    gru_body(B0, B1, Bx, c6, Hf, Hr, Xf, Xr, Xm1, p, blockIdx.x, threadIdx.x, lds);
    grid.sync();
  }
}

// fallback: one launch per step
__global__ __launch_bounds__(512) void k_gru_s(const uint16_t* __restrict__ B0, const uint16_t* __restrict__ B1,
                                               const uint16_t* __restrict__ Bx, const float* __restrict__ c6,
                                               float* Hf, uint16_t* Hr, float* Xf, uint16_t* Xr,
                                               const uint16_t* __restrict__ Xm1, int p) {
  __shared__ float lds[4 * 6144];
  gru_body(B0, B1, Bx, c6, Hf, Hr, Xf, Xr, Xm1, p, blockIdx.x, threadIdx.x, lds);
}

// ---------------------------------------------------------------- generic multi-word GEMM
// A row-major [M][lda], words at w*koffA. B = B^T row-major [N][ldb], words at w*koffB.
// Accumulates all products a_i * b_j with i+j <= CUT.
template <int WF32, int WPAIR, int BIAS, int RESIDF, int LEAKY, int SCALE, int VLAY,
          int AW, int BW, int CUT>
__global__ __launch_bounds__(256) void k_gemmX(const uint16_t* __restrict__ A, int lda, long long bsA, int koffA,
                                               const uint16_t* __restrict__ B, int ldb, long long bsB, int koffB,
                                               float* __restrict__ C, int ldc, long long bsC,
                                               uint16_t* __restrict__ Cb, int ldcb, long long bsCb, int pairoff,
                                               const float* __restrict__ bias, long long bsBias,
                                               float scale, int nk, int Nvalid) {
  int tid = threadIdx.x, w = tid >> 6, l = tid & 63, lr = l & 15, lg = l >> 4;
  long long bz = blockIdx.z;
  int brow = blockIdx.x * 128, bcol = blockIdx.y * 128;
  const uint16_t* Ab = A + bz * bsA;
  const uint16_t* Bb = B + bz * bsB;
  const float* biasz = bias ? bias + bz * bsBias : bias;
  __shared__ uint16_t sm[(AW + BW) * 4096];
  char* L = (char*)sm;
  f32x4 acc[4][4] = {};
  int wr = (w >> 1) * 64, wc = (w & 1) * 64;
  int srow = tid >> 2, skoff = (tid & 3) * 8;
  for (int ks = 0; ks < nk; ks++) {
    __syncthreads();
    int k0 = ks * 32 + skoff;
#pragma unroll
    for (int aw = 0; aw < AW; aw++) {
      stage16(Ab + (long long)(brow + srow) * lda + aw * koffA + k0,      L + aw * 8192 + w * 1024);
      stage16(Ab + (long long)(brow + 64 + srow) * lda + aw * koffA + k0, L + aw * 8192 + 4096 + w * 1024);
    }
#pragma unroll
    for (int bw = 0; bw < BW; bw++) {
      stage16(Bb + (long long)(bcol + srow) * ldb + bw * koffB + k0,      L + (AW + bw) * 8192 + w * 1024);
      stage16(Bb + (long long)(bcol + 64 + srow) * ldb + bw * koffB + k0, L + (AW + bw) * 8192 + 4096 + w * 1024);
    }
    __syncthreads();
    short8 af[AW][4], bf[BW][4];
#pragma unroll
    for (int aw = 0; aw < AW; aw++)
#pragma unroll
      for (int mi = 0; mi < 4; mi++)
        af[aw][mi] = *(short8*)(L + aw * 8192 + ((wr + mi * 16 + lr) * 32 + lg * 8) * 2);
#pragma unroll
    for (int bw = 0; bw < BW; bw++)
#pragma unroll
      for (int ni = 0; ni < 4; ni++)
        bf[bw][ni] = *(short8*)(L + (AW + bw) * 8192 + ((wc + ni * 16 + lr) * 32 + lg * 8) * 2);
#pragma unroll
    for (int mi = 0; mi < 4; mi++)
#pragma unroll
      for (int ni = 0; ni < 4; ni++)
#pragma unroll
        for (int iw = 0; iw < AW; iw++)
#pragma unroll
          for (int jw = 0; jw < BW; jw++)
            if (iw + jw <= CUT)
              acc[mi][ni] = __builtin_amdgcn_mfma_f32_16x16x32_bf16(af[iw][mi], bf[jw][ni], acc[mi][ni], 0, 0, 0);
  }
#pragma unroll
  for (int mi = 0; mi < 4; mi++) {
#pragma unroll
    for (int ni = 0; ni < 4; ni++) {
      int row0 = brow + wr + mi * 16 + 4 * lg;
      int col = bcol + wc + ni * 16 + lr;
      if (col < Nvalid) {
#pragma unroll
        for (int rg = 0; rg < 4; rg++) {
          float v = acc[mi][ni][rg];
          if (SCALE) v *= scale;
          if (BIAS == 1) v += biasz[col];
          if (BIAS == 2) v += biasz[row0 + rg];
          if (RESIDF) {
            long long ci = bz * bsC + (long long)(row0 + rg) * ldc + col;
            v += C[ci];
            C[ci] = v;
          }
          if (LEAKY) v = (v > 0.f) ? v : 0.01f * v;
          if (WF32) C[bz * bsC + (long long)(row0 + rg) * ldc + col] = v;
          if (WPAIR) {
            long long cbi = bz * bsCb + (long long)(row0 + rg) * ldcb + col;
            pair_store(Cb, cbi, cbi + pairoff, v);
          }
          if (VLAY) {  // V^T pair layout per 512-batch: [bz2][d 1024][hi 512 | lo 512]
            int bz2 = col >> 9, t = col & 511;
            long long vi = (long long)bz2 * 1048576 + (long long)(row0 + rg) * 1024 + t;
            pair_store(Cb, vi, vi + 512, v);
          }
        }
      }
    }
  }
}

// ---------------------------------------------------------------- softmax (rows of 512), P pair overlays scr
__global__ __launch_bounds__(256) void k_softmax(float* __restrict__ sc, int causal) {
  int r = blockIdx.x * 4 + (threadIdx.x >> 6);
  int l = threadIdx.x & 63;
  int s = r & 511;
  long long base = (long long)r * 512;
  int t0 = l * 8;
  float4 p0 = *(const float4*)&sc[base + t0];
  float4 p1 = *(const float4*)&sc[base + t0 + 4];
  float v[8] = {p0.x, p0.y, p0.z, p0.w, p1.x, p1.y, p1.z, p1.w};
  float m = -3.0e38f;
#pragma unroll
  for (int i = 0; i < 8; i++) {
    bool ok = (!causal) || (t0 + i <= s);
    if (ok) m = fmaxf(m, v[i]);
  }
#pragma unroll
  for (int o = 32; o > 0; o >>= 1) m = fmaxf(m, __shfl_xor(m, o));
  float e[8];
  float sum = 0.f;
#pragma unroll
  for (int i = 0; i < 8; i++) {
    bool ok = (!causal) || (t0 + i <= s);
    e[i] = ok ? __expf(v[i] - m) : 0.f;
    sum += e[i];
  }
#pragma unroll
  for (int o = 32; o > 0; o >>= 1) sum += __shfl_xor(sum, o);
  float inv = 1.f / sum;
  short8 oh, ol;
#pragma unroll
  for (int i = 0; i < 8; i++) {
    float p = e[i] * inv;
    uint16_t hi = f2bf(p);
    oh[i] = hi; ol[i] = (short)f2bf(p - bf2f(hi));
  }
  uint16_t* P = (uint16_t*)sc;   // single wave owns the row: loads done before stores
  long long pb = (long long)r * 1024;
  *(short8*)&P[pb + t0] = oh;
  *(short8*)&P[pb + 512 + t0] = ol;
}

// ---------------------------------------------------------------- host
extern "C" void kernel_launch(void* const* d_in, const int* in_sizes, int n_in,
                              void* d_out, int out_size, void* d_ws, size_t ws_size,
                              hipStream_t stream) {
  const float* h    = (const float*)d_in[0];
  const float* gt   = (const float*)d_in[1];
  const float* W_ih = (const float*)d_in[3];
  const float* W_hh = (const float*)d_in[4];
  const float* b_ih = (const float*)d_in[5];
  const float* b_hh = (const float*)d_in[6];
  const float* tp_W = (const float*)d_in[7];
  const float* tp_b = (const float*)d_in[8];
  const float* tQ_W = (const float*)d_in[9];
  const float* tQ_b = (const float*)d_in[10];
  const float* tK_W = (const float*)d_in[11];
  const float* tK_b = (const float*)d_in[12];
  const float* tV_W = (const float*)d_in[13];
  const float* tV_b = (const float*)d_in[14];
  const float* sQ_W = (const float*)d_in[15];
  const float* sQ_b = (const float*)d_in[16];
  const float* sK_W = (const float*)d_in[17];
  const float* sK_b = (const float*)d_in[18];
  const float* sV_W = (const float*)d_in[19];
  const float* sV_b = (const float*)d_in[20];
  const float* mlp_W= (const float*)d_in[21];
  const float* mlp_b= (const float*)d_in[22];
  const float* lin_W= (const float*)d_in[23];
  const float* lin_b= (const float*)d_in[24];
  (void)in_sizes; (void)n_in;

  char* wsb = (char*)d_ws;
  size_t off = 0;
  auto carve = [&](size_t bytes) -> void* {
    void* p = wsb + off;
    off += (bytes + 255) & ~(size_t)255;
    return p;
  };
  // Wreg: phase1 GRU packs (B0,B1 27.5MB + Bx 0.6MB) / phase2 pair weights + scr + Xs (27.3MB)
  char* Wreg = (char*)carve(28114944);
  uint16_t* B0 = (uint16_t*)Wreg;
  uint16_t* B1 = (uint16_t*)(Wreg + 13762560);
  uint16_t* Bx = (uint16_t*)(Wreg + 27525120);
  uint16_t* tQ2 = (uint16_t*)(Wreg);                    // pair; tK2 adjacent for z=2 launch
  uint16_t* sQ2 = (uint16_t*)(Wreg + 8388608);
  uint16_t* mlp2= (uint16_t*)(Wreg + 12582912);
  uint16_t* sK2 = (uint16_t*)(Wreg + 16777216);
  uint16_t* tV2 = (uint16_t*)(Wreg + 17170432);
  uint16_t* sV2 = (uint16_t*)(Wreg + 21364736);
  uint16_t* lin2= (uint16_t*)(Wreg + 21757952);
  float* scr    = (float*)(Wreg + 22282240);            // 4 MB chunk scores; P pair overlays
  uint16_t* Xs  = (uint16_t*)(Wreg + 26476544);         // 0.75 MB chunk X pair
  float* c6m    = (float*)carve(6240 * 4);
  float* Hf     = (float*)carve(32768LL * 1024 * 4);    // 128MB exact f32 H
  float* Xf     = (float*)carve(32768LL * 96 * 4);      // 12MB  exact f32 X
  uint16_t* Hr  = (uint16_t*)carve(2 * 64 * 3072 * 2);  // rolling h triple (ping-pong)
  uint16_t* Xr  = (uint16_t*)carve(2 * 64 * 288 * 2);   // rolling x triple
  uint16_t* Xm1 = (uint16_t*)carve(64 * 288 * 2);
  float* bias2  = (float*)carve(2048 * 4);              // merged tQ_b|tK_b
  uint16_t* Hs  = (uint16_t*)carve(2048LL * 2048 * 2);  // 8MB chunk H pair
  uint16_t* Qc  = (uint16_t*)carve(2048LL * 2048 * 2);  // 8MB chunk Q pair (Kc adjacent)
  uint16_t* Kc  = (uint16_t*)carve(2048LL * 2048 * 2);  // 8MB chunk K pair
  uint16_t* Vc  = (uint16_t*)carve(4LL * 1024 * 1024 * 2); // 8MB chunk V^T pair [4][1024][1024]
  size_t need = off;  // ~201 MB
  if (ws_size < need) {
    k_fill<<<dim3((out_size + 255) / 256), 256, 0, stream>>>((float*)d_out, out_size,
                                                             50000.0f + (float)(ws_size >> 20));
    return;
  }

  // ---- phase 1 prep
  k_pack<<<dim3(3360), 256, 0, stream>>>(W_hh, W_ih, tp_W, B0, B1);
  k_packx<<<dim3(48), 256, 0, stream>>>(tp_W, Bx);
  k_c6<<<dim3(25), 256, 0, stream>>>(b_ih, b_hh, W_ih, tp_b, c6m);
  k_init<<<dim3(280), 256, 0, stream>>>(h, gt, Hf, Hr, Xf, Xr);
  k_xm1<<<dim3(24), 256, 0, stream>>>(h, gt, tp_W, tp_b, Xm1);

  // ---- phase 1: GRU scan — persistent cooperative launch, fallback to per-step
  {
    void* args[] = {&B0, &B1, &Bx, &c6m, &Hf, &Hr, &Xf, &Xr, &Xm1};
    hipError_t e = hipLaunchCooperativeKernel((void*)k_gru_p, dim3(66), dim3(512), args, 0, stream);
    if (e != hipSuccess) {
      for (int p = 0; p < 512; p++)
        k_gru_s<<<dim3(66), dim3(512), 0, stream>>>(B0, B1, Bx, c6m, Hf, Hr, Xf, Xr, Xm1, p);
    }
  }

  // ---- phase 2: 16 chunks x 2048 rows (4 batches each), all GEMMs X3 pair
  for (int i = 0; i < 2; i++) {
    k_fsplit<<<dim3(4096), 256, 0, stream>>>(tQ_W + (long long)i * 1048576, tQ2, 1024, 1024, 1024);
    k_fsplit<<<dim3(4096), 256, 0, stream>>>(tK_W + (long long)i * 1048576, tQ2 + 2097152, 1024, 1024, 1024);
    k_fsplit<<<dim3(4096), 256, 0, stream>>>(sQ_W + (long long)i * 1048576, sQ2, 1024, 1024, 1024);
    k_fsplit<<<dim3(4096), 256, 0, stream>>>(mlp_W + (long long)i * 1048576, mlp2, 1024, 1024, 1024);
    k_fsplit<<<dim3(384), 256, 0, stream>>>(sK_W + (long long)i * 98304, sK2, 1024, 96, 1024);
    k_fsplit<<<dim3(4096), 256, 0, stream>>>(tV_W + (long long)i * 1048576, tV2, 1024, 1024, 1024);
    k_fsplit<<<dim3(384), 256, 0, stream>>>(sV_W + (long long)i * 98304, sV2, 1024, 96, 1024);
    if (i == 1) k_fsplit<<<dim3(512), 256, 0, stream>>>(lin_W, lin2, 96, 1024, 128);
    k_cp4<<<dim3(1), 256, 0, stream>>>((const float4*)(tQ_b + i * 1024), (float4*)bias2, 256);
    k_cp4<<<dim3(1), 256, 0, stream>>>((const float4*)(tK_b + i * 1024), (float4*)(bias2 + 1024), 256);

    for (int c = 0; c < 16; c++) {
      float* Hc = Hf + (long long)c * 2048 * 1024;
      k_split2<<<dim3(8192), 256, 0, stream>>>(Hc, Hs, 2097152, 1024);
      // --- temporal (causal) ---
      k_gemmX<0,1,1,0,0,0,0, 2,2,1><<<dim3(16, 8, 2), 256, 0, stream>>>(
          Hs, 2048, 0, 1024, tQ2, 2048, 2097152, 1024, nullptr, 0, 0,
          Qc, 2048, 4194304, 1024, bias2, 1024, 0.f, 32, 1024);
      k_gemmX<0,0,2,0,0,0,1, 2,2,1><<<dim3(8, 16, 1), 256, 0, stream>>>(
          tV2, 2048, 0, 1024, Hs, 2048, 0, 1024, nullptr, 0, 0, Vc, 0, 0, 0,
          tV_b + i * 1024, 0, 0.f, 32, 2048);
      k_gemmX<1,0,0,0,0,1,0, 2,2,1><<<dim3(4, 4, 4), 256, 0, stream>>>(
          Qc, 2048, 1048576, 1024, Kc, 2048, 1048576, 1024, scr, 512, 262144,
          nullptr, 0, 0, 0, nullptr, 0, 0.03125f, 32, 512);
      k_softmax<<<dim3(512), 256, 0, stream>>>(scr, 1);
      k_gemmX<0,1,0,1,0,0,0, 2,2,1><<<dim3(4, 8, 4), 256, 0, stream>>>(
          (const uint16_t*)scr, 1024, 524288, 512, Vc, 1024, 1048576, 512,
          Hc, 1024, 524288, Hs, 2048, 1048576, 1024, nullptr, 0, 0.f, 16, 1024);
      // --- spatial (K/V from X) ---
      k_split2<<<dim3(768), 256, 0, stream>>>(Xf + (long long)c * 2048 * 96, Xs, 196608, 96);
      k_gemmX<0,1,1,0,0,0,0, 2,2,1><<<dim3(16, 8, 1), 256, 0, stream>>>(
          Hs, 2048, 0, 1024, sQ2, 2048, 0, 1024, nullptr, 0, 0,
          Qc, 2048, 0, 1024, sQ_b + i * 1024, 0, 0.f, 32, 1024);
      k_gemmX<0,1,1,0,0,0,0, 2,2,1><<<dim3(16, 8, 1), 256, 0, stream>>>(
          Xs, 192, 0, 96, sK2, 192, 0, 96, nullptr, 0, 0,
          Kc, 2048, 0, 1024, sK_b + i * 1024, 0, 0.f, 3, 1024);
      k_gemmX<0,0,2,0,0,0,1, 2,2,1><<<dim3(8, 16, 1), 256, 0, stream>>>(
          sV2, 192, 0, 96, Xs, 192, 0, 96, nullptr, 0, 0, Vc, 0, 0, 0,
          sV_b + i * 1024, 0, 0.f, 3, 2048);
      k_gemmX<1,0,0,0,0,1,0, 2,2,1><<<dim3(4, 4, 4), 256, 0, stream>>>(
          Qc, 2048, 1048576, 1024, Kc, 2048, 1048576, 1024, scr, 512, 262144,
          nullptr, 0, 0, 0, nullptr, 0, 0.03125f, 32, 512);
      k_softmax<<<dim3(512), 256, 0, stream>>>(scr, 0);
      k_gemmX<0,1,0,1,0,0,0, 2,2,1><<<dim3(4, 8, 4), 256, 0, stream>>>(
          (const uint16_t*)scr, 1024, 524288, 512, Vc, 1024, 1048576, 512,
          Hc, 1024, 524288, Hs, 2048, 1048576, 1024, nullptr, 0, 0.f, 16, 1024);
      // --- MLP: reads Hs, writes Hf (f32) + Qc (pair; head input) — no alias with Hs ---
      k_gemmX<1,1,1,0,1,0,0, 2,2,1><<<dim3(16, 8, 1), 256, 0, stream>>>(
          Hs, 2048, 0, 1024, mlp2, 2048, 0, 1024, Hc, 1024, 0,
          Qc, 2048, 0, 1024, mlp_b + i * 1024, 0, 0.f, 32, 1024);
      // --- head (layer 1): reads MLP pair output from Qc ---
      if (i == 1) {
        k_gemmX<1,0,1,0,0,0,0, 2,2,1><<<dim3(16, 1, 1), 256, 0, stream>>>(
            Qc, 2048, 0, 1024, lin2, 2048, 0, 1024,
            (float*)d_out + (long long)c * 2048 * 96, 96, 0,
            nullptr, 0, 0, 0, lin_b, 0, 0.f, 32, 96);
      }
    }
  }
}

// Round 12
// 26514.905 us; speedup vs baseline: 1.3765x; 1.3765x over previous
//
#include <hip/hip_runtime.h>
#include <stdint.h>

// Decoder_71880572665909 : GRU scan (T=511) + 2 x (causal self-attn + cross-attn + MLP) + linear head
// B=64, S=512, HID=1024, POSE=96, L=2.
// Round-12: revert coop-launch (r11 regression suspect); in-place f32->pair H/X conversion after
// the GRU kills all snapshot buffers/launches; 4096-row chunks double every phase-2 grid.
// Numerics: f32 GRU chains; pair-bf16 X3 GEMMs everywhere in phase 2 (r10/r11-proven). ~218 MiB.

typedef __attribute__((ext_vector_type(8))) short short8;
typedef __attribute__((ext_vector_type(4))) float f32x4;

__device__ __forceinline__ uint16_t f2bf(float f) {
  uint32_t u = __float_as_uint(f);
  uint32_t r = u + 0x7FFFu + ((u >> 16) & 1u);
  return (uint16_t)(r >> 16);
}
__device__ __forceinline__ float bf2f(uint16_t h) {
  return __uint_as_float(((uint32_t)h) << 16);
}
__device__ __forceinline__ float sigm(float x) { return 1.f / (1.f + __expf(-x)); }
__device__ __forceinline__ float tanh_(float x) { return 2.f / (1.f + __expf(-2.f * x)) - 1.f; }
__device__ __forceinline__ short8 ld8(const uint16_t* p) { return *(const short8*)p; }

__device__ __forceinline__ void stage16(const void* g, void* lds_base_uniform) {
  __builtin_amdgcn_global_load_lds((const __attribute__((address_space(1))) void*)g,
                                   (__attribute__((address_space(3))) void*)lds_base_uniform, 16, 0, 0);
}
__device__ __forceinline__ void tri_store(uint16_t* p, long long o0, long long o1, long long o2, float v) {
  uint16_t hi = f2bf(v);
  float r = v - bf2f(hi);
  uint16_t mid = f2bf(r);
  p[o0] = hi; p[o1] = mid; p[o2] = f2bf(r - bf2f(mid));
}
__device__ __forceinline__ void pair_store(uint16_t* p, long long o0, long long o1, float v) {
  uint16_t hi = f2bf(v);
  p[o0] = hi; p[o1] = f2bf(v - bf2f(hi));
}

// ---------------------------------------------------------------- prep / utility kernels

__global__ __launch_bounds__(256) void k_fill(float* __restrict__ o, int n, float v) {
  int i = blockIdx.x * 256 + threadIdx.x;
  if (i < n) o[i] = v;
}

__global__ __launch_bounds__(256) void k_cp4(const float4* __restrict__ s, float4* __restrict__ d, int n4) {
  int i = blockIdx.x * 256 + threadIdx.x;
  if (i < n4) d[i] = s[i];
}

// in-place f32 row [1024] -> pair bf16 row [2048] (hi 1024 | lo 1024), same bytes. wave-per-row.
__global__ __launch_bounds__(512) void k_cvtH(float* __restrict__ Hf) {
  int r = blockIdx.x * 8 + (threadIdx.x >> 6);
  int l = threadIdx.x & 63;
  float* row = Hf + (long long)r * 1024;
  float v[16];
#pragma unroll
  for (int t = 0; t < 16; t++) v[t] = row[l + 64 * t];
  __syncthreads();
  uint16_t* o = (uint16_t*)row;
#pragma unroll
  for (int t = 0; t < 16; t++) {
    int j = l + 64 * t;
    uint16_t hi = f2bf(v[t]);
    o[j] = hi; o[1024 + j] = f2bf(v[t] - bf2f(hi));
  }
}

// in-place f32 row [96] -> pair bf16 row [192], same bytes. wave-per-row.
__global__ __launch_bounds__(512) void k_cvtX(float* __restrict__ Xf) {
  int r = blockIdx.x * 8 + (threadIdx.x >> 6);
  int l = threadIdx.x & 63;
  float* row = Xf + (long long)r * 96;
  float v0 = row[l];
  float v1 = (l < 32) ? row[64 + l] : 0.f;
  __syncthreads();
  uint16_t* o = (uint16_t*)row;
  uint16_t h0 = f2bf(v0);
  o[l] = h0; o[96 + l] = f2bf(v0 - bf2f(h0));
  if (l < 32) {
    uint16_t h1 = f2bf(v1);
    o[64 + l] = h1; o[160 + l] = f2bf(v1 - bf2f(h1));
  }
}

// f32 W [N][K] -> pair [Npad][2K]
__global__ __launch_bounds__(256) void k_fsplit(const float* __restrict__ s, uint16_t* __restrict__ d,
                                                int N, int K, int Npad) {
  int id = blockIdx.x * 256 + threadIdx.x;
  if (id >= Npad * K) return;
  int n = id / K, k = id % K;
  float w = (n < N) ? s[(long long)n * K + k] : 0.f;
  pair_store(d, (long long)n * 2 * K + k, (long long)n * 2 * K + K + k, w);
}

// x_{-1} = x0 - h0 @ tp_W^T - tp_b  (triple out; feeds step-0 gi)
__global__ __launch_bounds__(256) void k_xm1(const float* __restrict__ h, const float* __restrict__ gt,
                                             const float* __restrict__ tp_W, const float* __restrict__ tp_b,
                                             uint16_t* __restrict__ Xm1) {
  int id = blockIdx.x * 256 + threadIdx.x;
  if (id >= 64 * 96) return;
  int b = id / 96, c = id % 96;
  float s = gt[(long long)b * 512 * 96 + c] - tp_b[c];
  const float* hr = &h[(long long)b * 1024];
  const float* wr = &tp_W[(long long)c * 1024];
  for (int k = 0; k < 1024; k++) s -= hr[k] * wr[k];
  tri_store(Xm1, b * 288 + c, b * 288 + 96 + c, b * 288 + 192 + c, s);
}

// gates pack: K=1120 x N=6144 fragment order [384 tiles][35 ks][64][8], hi+mid planes
__global__ __launch_bounds__(256) void k_pack(const float* __restrict__ W_hh, const float* __restrict__ W_ih,
                                              const float* __restrict__ tp_W,
                                              uint16_t* __restrict__ B0, uint16_t* __restrict__ B1) {
  int id = blockIdx.x * 256 + threadIdx.x;
  if (id >= 384 * 35 * 64) return;
  int tile = id / 2240, rem = id % 2240;
  int ks = rem >> 6, l = rem & 63;
  int n = tile * 16 + (l & 15);
  int kb = ks * 32 + (l >> 4) * 8;
  short8 v0, v1;
#pragma unroll
  for (int i = 0; i < 8; i++) {
    int k = kb + i;
    float m = 0.f;
    if (n < 3072) {
      m = (k < 1024) ? W_hh[(long long)n * 1024 + k] : 0.f;
    } else {
      int j = n - 3072;
      if (k < 1024) {
        float s = 0.f;
        for (int q = 0; q < 96; q++) s += tp_W[q * 1024 + k] * W_ih[(long long)j * 96 + q];
        m = s;
      } else {
        m = W_ih[(long long)j * 96 + (k - 1024)];
      }
    }
    uint16_t hi = f2bf(m);
    v0[i] = (short)hi; v1[i] = (short)f2bf(m - bf2f(hi));
  }
  *(short8*)&B0[(long long)id * 8] = v0;
  *(short8*)&B1[(long long)id * 8] = v1;
}

// x-update pack: tp_W [6 tiles][32 ks][64][8], triple planes (plane stride 98304 u16)
__global__ __launch_bounds__(256) void k_packx(const float* __restrict__ tp_W, uint16_t* __restrict__ Bx) {
  int id = blockIdx.x * 256 + threadIdx.x;
  if (id >= 6 * 32 * 64) return;
  int tile = id / 2048, rem = id % 2048;
  int ks = rem >> 6, l = rem & 63;
  int c = tile * 16 + (l & 15);
  int lg = l >> 4;
  short8 v0, v1, v2;
#pragma unroll
  for (int i = 0; i < 8; i++) {
    int k = ks * 32 + lg * 8 + i;
    float w = tp_W[(long long)c * 1024 + k];
    uint16_t hi = f2bf(w);
    float r = w - bf2f(hi);
    uint16_t mid = f2bf(r);
    v0[i] = (short)hi; v1[i] = (short)mid; v2[i] = (short)f2bf(r - bf2f(mid));
  }
  *(short8*)&Bx[(long long)id * 8] = v0;
  *(short8*)&Bx[98304 + (long long)id * 8] = v1;
  *(short8*)&Bx[196608 + (long long)id * 8] = v2;
}

__global__ __launch_bounds__(256) void k_c6(const float* __restrict__ b_ih, const float* __restrict__ b_hh,
                                            const float* __restrict__ W_ih, const float* __restrict__ tp_b,
                                            float* __restrict__ c6m) {
  int n = blockIdx.x * 256 + threadIdx.x;
  if (n >= 6240) return;
  float m;
  if (n < 3072) { m = b_hh[n]; }
  else if (n < 6144) {
    int j = n - 3072;
    float s = 0.f;
    for (int q = 0; q < 96; q++) s += W_ih[(long long)j * 96 + q] * tp_b[q];
    m = b_ih[j] + s;
  } else { m = tp_b[n - 6144]; }
  c6m[n] = m;
}

__global__ __launch_bounds__(256) void k_init(const float* __restrict__ h, const float* __restrict__ gt,
                                              float* Hf, uint16_t* Hr, float* Xf, uint16_t* Xr) {
  int id = blockIdx.x * 256 + threadIdx.x;
  if (id < 65536) {
    int b = id >> 10, d = id & 1023;
    float v = h[id];
    Hf[((long long)b * 512) * 1024 + d] = v;
    tri_store(Hr, b * 3072 + d, b * 3072 + 1024 + d, b * 3072 + 2048 + d, v);
  } else {
    int r2 = id - 65536;
    if (r2 < 6144) {
      int b = r2 / 96, c = r2 % 96;
      float v = gt[(long long)b * 512 * 96 + c];
      Xf[((long long)b * 512) * 96 + c] = v;
      tri_store(Xr, b * 288 + c, b * 288 + 96 + c, b * 288 + 192 + c, v);
    }
  }
}

// ---------------------------------------------------------------- GRU step (one launch per step)
// grid 66: blocks 0..63 gates (16 j-cols x 6 strips), blocks 64,65 x-update (48 cols each).
__global__ __launch_bounds__(512) void k_gru(const uint16_t* __restrict__ B0, const uint16_t* __restrict__ B1,
                                             const uint16_t* __restrict__ Bx, const float* __restrict__ c6,
                                             float* Hf, uint16_t* Hr, float* Xf, uint16_t* Xr,
                                             const uint16_t* __restrict__ Xm1, int p) {
  int tid = threadIdx.x, w = tid >> 6, l = tid & 63, lr = l & 15, lg = l >> 4;
  int blk = blockIdx.x;
  const uint16_t* Hcur = Hr + (p & 1) * 196608;
  uint16_t* Hnxt = Hr + ((p + 1) & 1) * 196608;
  uint16_t* Xw = Xr + (p & 1) * 18432;
  const uint16_t* Xg = (p == 0) ? Xm1 : (Xr + ((p - 1) & 1) * 18432);
  __shared__ float lds[4 * 6144];

  if (blk >= 64) {  // x-update: x_p = x_{p-1} + h_p @ tpW^T + tp_b ; X6 precision
    if (p < 1) return;
    int xb = blk - 64;
    if (w < 6) {
      int tl = xb * 3 + (w >> 1);
      int kh = w & 1;
      f32x4 ac[4] = {};
      for (int ks = kh * 16; ks < kh * 16 + 16; ks++) {
        short8 a0[4], a1[4], a2[4];
        int k0 = ks * 32 + lg * 8;
#pragma unroll
        for (int rt = 0; rt < 4; rt++) {
          int hb = (rt * 16 + lr) * 3072;
          a0[rt] = ld8(&Hcur[hb + k0]);
          a1[rt] = ld8(&Hcur[hb + 1024 + k0]);
          a2[rt] = ld8(&Hcur[hb + 2048 + k0]);
        }
        long long bo = (((long long)tl * 32 + ks) * 64 + l) * 8;
        short8 b0 = ld8(&Bx[bo]);
        short8 b1 = ld8(&Bx[98304 + bo]);
        short8 b2 = ld8(&Bx[196608 + bo]);
#pragma unroll
        for (int rt = 0; rt < 4; rt++) {
          ac[rt] = __builtin_amdgcn_mfma_f32_16x16x32_bf16(a0[rt], b0, ac[rt], 0, 0, 0);
          ac[rt] = __builtin_amdgcn_mfma_f32_16x16x32_bf16(a0[rt], b1, ac[rt], 0, 0, 0);
          ac[rt] = __builtin_amdgcn_mfma_f32_16x16x32_bf16(a1[rt], b0, ac[rt], 0, 0, 0);
          ac[rt] = __builtin_amdgcn_mfma_f32_16x16x32_bf16(a1[rt], b1, ac[rt], 0, 0, 0);
          ac[rt] = __builtin_amdgcn_mfma_f32_16x16x32_bf16(a0[rt], b2, ac[rt], 0, 0, 0);
          ac[rt] = __builtin_amdgcn_mfma_f32_16x16x32_bf16(a2[rt], b0, ac[rt], 0, 0, 0);
        }
      }
#pragma unroll
      for (int rt = 0; rt < 4; rt++)
#pragma unroll
        for (int rg = 0; rg < 4; rg++)
          lds[w * 1024 + (rt * 16 + 4 * lg + rg) * 16 + lr] = ac[rt][rg];
    }
    __syncthreads();
    for (int idx = tid; idx < 3072; idx += 512) {
      int ti = idx >> 10, rem = idx & 1023;
      int row = rem >> 4, cl = rem & 15;
      float v = lds[(2 * ti) * 1024 + row * 16 + cl] + lds[(2 * ti + 1) * 1024 + row * 16 + cl];
      int c = (xb * 3 + ti) * 16 + cl;
      float xold = Xf[((long long)row * 512 + p - 1) * 96 + c];
      float xv = v + c6[6144 + c] + xold;
      Xf[((long long)row * 512 + p) * 96 + c] = xv;
      tri_store(Xw, row * 288 + c, row * 288 + 96 + c, row * 288 + 192 + c, xv);
    }
    return;
  }

  if (p >= 511) return;
  // gates: j in [blk*16, +16); tiles s*64+blk for s=0..5. 8 waves split K(35 ks). X3 pair-weights.
  int ks0 = (w * 35) >> 3, ks1 = ((w + 1) * 35) >> 3;
  f32x4 acc[6][4] = {};
  for (int ks = ks0; ks < ks1; ks++) {
    short8 a0[4], a1[4];
    if (ks < 32) {
      int k0 = ks * 32 + lg * 8;
#pragma unroll
      for (int rt = 0; rt < 4; rt++) {
        int hb = (rt * 16 + lr) * 3072;
        a0[rt] = ld8(&Hcur[hb + k0]);
        a1[rt] = ld8(&Hcur[hb + 1024 + k0]);
      }
    } else {
      int k0 = (ks - 32) * 32 + lg * 8;
#pragma unroll
      for (int rt = 0; rt < 4; rt++) {
        int xb2 = (rt * 16 + lr) * 288;
        a0[rt] = ld8(&Xg[xb2 + k0]);
        a1[rt] = ld8(&Xg[xb2 + 96 + k0]);
      }
    }
#pragma unroll
    for (int t = 0; t < 6; t++) {
      long long bo = (((long long)(t * 64 + blk)) * 35 + ks) * 64 * 8 + (long long)l * 8;
      short8 b0 = ld8(&B0[bo]);
      short8 b1 = ld8(&B1[bo]);
#pragma unroll
      for (int rt = 0; rt < 4; rt++) {
        acc[t][rt] = __builtin_amdgcn_mfma_f32_16x16x32_bf16(a0[rt], b0, acc[t][rt], 0, 0, 0);
        acc[t][rt] = __builtin_amdgcn_mfma_f32_16x16x32_bf16(a0[rt], b1, acc[t][rt], 0, 0, 0);
        acc[t][rt] = __builtin_amdgcn_mfma_f32_16x16x32_bf16(a1[rt], b0, acc[t][rt], 0, 0, 0);
      }
    }
  }
  int slab = w & 3;
  if (w < 4) {
#pragma unroll
    for (int t = 0; t < 6; t++)
#pragma unroll
      for (int rt = 0; rt < 4; rt++)
#pragma unroll
        for (int rg = 0; rg < 4; rg++)
          lds[slab * 6144 + (rt * 16 + 4 * lg + rg) * 96 + t * 16 + lr] = acc[t][rt][rg];
  }
  __syncthreads();
  if (w >= 4) {
#pragma unroll
    for (int t = 0; t < 6; t++)
#pragma unroll
      for (int rt = 0; rt < 4; rt++)
#pragma unroll
        for (int rg = 0; rg < 4; rg++)
          lds[slab * 6144 + (rt * 16 + 4 * lg + rg) * 96 + t * 16 + lr] += acc[t][rt][rg];
  }
  __syncthreads();
  for (int idx = tid; idx < 6144; idx += 512)
    lds[idx] = lds[idx] + lds[6144 + idx] + lds[12288 + idx] + lds[18432 + idx];
  __syncthreads();
  for (int item = tid; item < 1024; item += 512) {
    int b = item >> 4, jj = item & 15;
    int j = blk * 16 + jj;
    const float* row = &lds[b * 96];
    float hr = row[jj]       + c6[j];
    float hz = row[16 + jj]  + c6[1024 + j];
    float hnn = row[32 + jj] + c6[2048 + j];
    float ir = row[48 + jj]  + c6[3072 + j];
    float iz = row[64 + jj]  + c6[4096 + j];
    float inn = row[80 + jj] + c6[5120 + j];
    float hp = Hf[((long long)b * 512 + p) * 1024 + j];
    float r = sigm(ir + hr), z = sigm(iz + hz);
    float nn = tanh_(inn + r * hnn);
    float hv = (1.f - z) * nn + z * hp;
    Hf[((long long)b * 512 + p + 1) * 1024 + j] = hv;
    tri_store(Hnxt, b * 3072 + j, b * 3072 + 1024 + j, b * 3072 + 2048 + j, hv);
  }
}

// ---------------------------------------------------------------- generic multi-word GEMM
// A row-major [M][lda], words at w*koffA. B = B^T row-major [N][ldb], words at w*koffB.
// Products a_i*b_j with i+j <= CUT. Epilogue: SCALE -> BIAS -> RESIDP(pair Cb) -> LEAKY ->
// {WF32 C, WPAIR Cb, SNAP Cb2, VLAY Cb}.
template <int WF32, int WPAIR, int BIAS, int RESIDP, int LEAKY, int SCALE, int VLAY, int SNAP,
          int AW, int BW, int CUT>
__global__ __launch_bounds__(256) void k_gemmX(const uint16_t* __restrict__ A, int lda, long long bsA, int koffA,
                                               const uint16_t* __restrict__ B, int ldb, long long bsB, int koffB,
                                               float* __restrict__ C, int ldc, long long bsC,
                                               uint16_t* __restrict__ Cb, int ldcb, long long bsCb, int pairoff,
                                               uint16_t* __restrict__ Cb2, int ldcb2, long long bsCb2, int pairoff2,
                                               const float* __restrict__ bias, long long bsBias,
                                               float scale, int nk, int Nvalid) {
  int tid = threadIdx.x, w = tid >> 6, l = tid & 63, lr = l & 15, lg = l >> 4;
  long long bz = blockIdx.z;
  int brow = blockIdx.x * 128, bcol = blockIdx.y * 128;
  const uint16_t* Ab = A + bz * bsA;
  const uint16_t* Bb = B + bz * bsB;
  const float* biasz = bias ? bias + bz * bsBias : bias;
  __shared__ uint16_t sm[(AW + BW) * 4096];
  char* L = (char*)sm;
  f32x4 acc[4][4] = {};
  int wr = (w >> 1) * 64, wc = (w & 1) * 64;
  int srow = tid >> 2, skoff = (tid & 3) * 8;
  for (int ks = 0; ks < nk; ks++) {
    __syncthreads();
    int k0 = ks * 32 + skoff;
#pragma unroll
    for (int aw = 0; aw < AW; aw++) {
      stage16(Ab + (long long)(brow + srow) * lda + aw * koffA + k0,      L + aw * 8192 + w * 1024);
      stage16(Ab + (long long)(brow + 64 + srow) * lda + aw * koffA + k0, L + aw * 8192 + 4096 + w * 1024);
    }
#pragma unroll
    for (int bw = 0; bw < BW; bw++) {
      stage16(Bb + (long long)(bcol + srow) * ldb + bw * koffB + k0,      L + (AW + bw) * 8192 + w * 1024);
      stage16(Bb + (long long)(bcol + 64 + srow) * ldb + bw * koffB + k0, L + (AW + bw) * 8192 + 4096 + w * 1024);
    }
    __syncthreads();
    short8 af[AW][4], bf[BW][4];
#pragma unroll
    for (int aw = 0; aw < AW; aw++)
#pragma unroll
      for (int mi = 0; mi < 4; mi++)
        af[aw][mi] = *(short8*)(L + aw * 8192 + ((wr + mi * 16 + lr) * 32 + lg * 8) * 2);
#pragma unroll
    for (int bw = 0; bw < BW; bw++)
#pragma unroll
      for (int ni = 0; ni < 4; ni++)
        bf[bw][ni] = *(short8*)(L + (AW + bw) * 8192 + ((wc + ni * 16 + lr) * 32 + lg * 8) * 2);
#pragma unroll
    for (int mi = 0; mi < 4; mi++)
#pragma unroll
      for (int ni = 0; ni < 4; ni++)
#pragma unroll
        for (int iw = 0; iw < AW; iw++)
#pragma unroll
          for (int jw = 0; jw < BW; jw++)
            if (iw + jw <= CUT)
              acc[mi][ni] = __builtin_amdgcn_mfma_f32_16x16x32_bf16(af[iw][mi], bf[jw][ni], acc[mi][ni], 0, 0, 0);
  }
#pragma unroll
  for (int mi = 0; mi < 4; mi++) {
#pragma unroll
    for (int ni = 0; ni < 4; ni++) {
      int row0 = brow + wr + mi * 16 + 4 * lg;
      int col = bcol + wc + ni * 16 + lr;
      if (col < Nvalid) {
#pragma unroll
        for (int rg = 0; rg < 4; rg++) {
          float v = acc[mi][ni][rg];
          if (SCALE) v *= scale;
          if (BIAS == 1) v += biasz[col];
          if (BIAS == 2) v += biasz[row0 + rg];
          long long cbi = 0;
          if (WPAIR || RESIDP) cbi = bz * bsCb + (long long)(row0 + rg) * ldcb + col;
          if (RESIDP) v += bf2f(Cb[cbi]) + bf2f(Cb[cbi + pairoff]);
          if (LEAKY) v = (v > 0.f) ? v : 0.01f * v;
          if (WF32) C[bz * bsC + (long long)(row0 + rg) * ldc + col] = v;
          if (WPAIR) pair_store(Cb, cbi, cbi + pairoff, v);
          if (SNAP) {
            long long c2 = bz * bsCb2 + (long long)(row0 + rg) * ldcb2 + col;
            pair_store(Cb2, c2, c2 + pairoff2, v);
          }
          if (VLAY) {  // V^T pair layout per 512-batch: [bz2][d 1024][hi 512 | lo 512]
            int bz2 = col >> 9, t = col & 511;
            long long vi = (long long)bz2 * 1048576 + (long long)(row0 + rg) * 1024 + t;
            pair_store(Cb, vi, vi + 512, v);
          }
        }
      }
    }
  }
}

// ---------------------------------------------------------------- softmax (rows of 512), P pair overlays scr
__global__ __launch_bounds__(256) void k_softmax(float* __restrict__ sc, int causal) {
  int r = blockIdx.x * 4 + (threadIdx.x >> 6);
  int l = threadIdx.x & 63;
  int s = r & 511;
  long long base = (long long)r * 512;
  int t0 = l * 8;
  float4 p0 = *(const float4*)&sc[base + t0];
  float4 p1 = *(const float4*)&sc[base + t0 + 4];
  float v[8] = {p0.x, p0.y, p0.z, p0.w, p1.x, p1.y, p1.z, p1.w};
  float m = -3.0e38f;
#pragma unroll
  for (int i = 0; i < 8; i++) {
    bool ok = (!causal) || (t0 + i <= s);
    if (ok) m = fmaxf(m, v[i]);
  }
#pragma unroll
  for (int o = 32; o > 0; o >>= 1) m = fmaxf(m, __shfl_xor(m, o));
  float e[8];
  float sum = 0.f;
#pragma unroll
  for (int i = 0; i < 8; i++) {
    bool ok = (!causal) || (t0 + i <= s);
    e[i] = ok ? __expf(v[i] - m) : 0.f;
    sum += e[i];
  }
#pragma unroll
  for (int o = 32; o > 0; o >>= 1) sum += __shfl_xor(sum, o);
  float inv = 1.f / sum;
  short8 oh, ol;
#pragma unroll
  for (int i = 0; i < 8; i++) {
    float p = e[i] * inv;
    uint16_t hi = f2bf(p);
    oh[i] = hi; ol[i] = (short)f2bf(p - bf2f(hi));
  }
  uint16_t* P = (uint16_t*)sc;   // single wave owns the row: loads done before stores
  long long pb = (long long)r * 1024;
  *(short8*)&P[pb + t0] = oh;
  *(short8*)&P[pb + 512 + t0] = ol;
}

// ---------------------------------------------------------------- host
extern "C" void kernel_launch(void* const* d_in, const int* in_sizes, int n_in,
                              void* d_out, int out_size, void* d_ws, size_t ws_size,
                              hipStream_t stream) {
  const float* h    = (const float*)d_in[0];
  const float* gt   = (const float*)d_in[1];
  const float* W_ih = (const float*)d_in[3];
  const float* W_hh = (const float*)d_in[4];
  const float* b_ih = (const float*)d_in[5];
  const float* b_hh = (const float*)d_in[6];
  const float* tp_W = (const float*)d_in[7];
  const float* tp_b = (const float*)d_in[8];
  const float* tQ_W = (const float*)d_in[9];
  const float* tQ_b = (const float*)d_in[10];
  const float* tK_W = (const float*)d_in[11];
  const float* tK_b = (const float*)d_in[12];
  const float* tV_W = (const float*)d_in[13];
  const float* tV_b = (const float*)d_in[14];
  const float* sQ_W = (const float*)d_in[15];
  const float* sQ_b = (const float*)d_in[16];
  const float* sK_W = (const float*)d_in[17];
  const float* sK_b = (const float*)d_in[18];
  const float* sV_W = (const float*)d_in[19];
  const float* sV_b = (const float*)d_in[20];
  const float* mlp_W= (const float*)d_in[21];
  const float* mlp_b= (const float*)d_in[22];
  const float* lin_W= (const float*)d_in[23];
  const float* lin_b= (const float*)d_in[24];
  (void)in_sizes; (void)n_in;

  char* wsb = (char*)d_ws;
  size_t off = 0;
  auto carve = [&](size_t bytes) -> void* {
    void* p = wsb + off;
    off += (bytes + 255) & ~(size_t)255;
    return p;
  };
  // Wreg: phase-1 GRU packs (28.1MB) / phase-2 pair weights (21.25MB) + scr (8MB)
  char* Wreg = (char*)carve(30670848);
  uint16_t* B0 = (uint16_t*)Wreg;
  uint16_t* B1 = (uint16_t*)(Wreg + 13762560);
  uint16_t* Bx = (uint16_t*)(Wreg + 27525120);
  uint16_t* tQ2 = (uint16_t*)(Wreg);                    // pair; tK2 adjacent at +4194304 B
  uint16_t* sQ2 = (uint16_t*)(Wreg + 8388608);
  uint16_t* mlp2= (uint16_t*)(Wreg + 12582912);
  uint16_t* sK2 = (uint16_t*)(Wreg + 16777216);
  uint16_t* tV2 = (uint16_t*)(Wreg + 17170432);
  uint16_t* sV2 = (uint16_t*)(Wreg + 21364736);
  uint16_t* lin2= (uint16_t*)(Wreg + 21757952);
  float* scr    = (float*)(Wreg + 22282240);            // 8 MB chunk scores; P pair overlays
  float* c6m    = (float*)carve(6240 * 4);
  float* Hf     = (float*)carve(32768LL * 1024 * 4);    // 128MB f32 H (phase 1) -> pair Hp (phase 2)
  float* Xf     = (float*)carve(32768LL * 96 * 4);      // 12MB  f32 X (phase 1) -> pair Xp (phase 2)
  uint16_t* Hr  = (uint16_t*)carve(2 * 64 * 3072 * 2);  // rolling h triple (ping-pong)
  uint16_t* Xr  = (uint16_t*)carve(2 * 64 * 288 * 2);   // rolling x triple
  uint16_t* Xm1 = (uint16_t*)carve(64 * 288 * 2);
  float* bias2  = (float*)carve(2048 * 4);              // merged tQ_b|tK_b
  uint16_t* Qc  = (uint16_t*)carve(4096LL * 2048 * 2);  // 16MB chunk Q pair (Kc adjacent for z=2)
  uint16_t* Kc  = (uint16_t*)carve(4096LL * 2048 * 2);  // 16MB chunk K pair
  uint16_t* Vc  = (uint16_t*)carve(8LL * 1024 * 1024 * 2); // 16MB chunk V^T pair [8][1024][1024]
  size_t need = off;  // ~218 MiB
  if (ws_size < need) {
    k_fill<<<dim3((out_size + 255) / 256), 256, 0, stream>>>((float*)d_out, out_size,
                                                             50000.0f + (float)(ws_size >> 20));
    return;
  }
  uint16_t* Hp = (uint16_t*)Hf;   // phase-2 pair view (in-place converted)
  uint16_t* Xp = (uint16_t*)Xf;

  // ---- phase 1 prep
  k_pack<<<dim3(3360), 256, 0, stream>>>(W_hh, W_ih, tp_W, B0, B1);
  k_packx<<<dim3(48), 256, 0, stream>>>(tp_W, Bx);
  k_c6<<<dim3(25), 256, 0, stream>>>(b_ih, b_hh, W_ih, tp_b, c6m);
  k_init<<<dim3(280), 256, 0, stream>>>(h, gt, Hf, Hr, Xf, Xr);
  k_xm1<<<dim3(24), 256, 0, stream>>>(h, gt, tp_W, tp_b, Xm1);

  // ---- phase 1: GRU scan (step p: gates -> h_{p+1}; x-update -> x_p)
  for (int p = 0; p < 512; p++)
    k_gru<<<dim3(66), dim3(512), 0, stream>>>(B0, B1, Bx, c6m, Hf, Hr, Xf, Xr, Xm1, p);

  // ---- convert trajectories in place: f32 -> pair bf16 (same bytes)
  k_cvtH<<<dim3(4096), 512, 0, stream>>>(Hf);
  k_cvtX<<<dim3(4096), 512, 0, stream>>>(Xf);

  // ---- phase 2: 8 chunks x 4096 rows (8 batches each), all GEMMs X3 pair
  for (int i = 0; i < 2; i++) {
    k_fsplit<<<dim3(4096), 256, 0, stream>>>(tQ_W + (long long)i * 1048576, tQ2, 1024, 1024, 1024);
    k_fsplit<<<dim3(4096), 256, 0, stream>>>(tK_W + (long long)i * 1048576, tQ2 + 2097152, 1024, 1024, 1024);
    k_fsplit<<<dim3(4096), 256, 0, stream>>>(sQ_W + (long long)i * 1048576, sQ2, 1024, 1024, 1024);
    k_fsplit<<<dim3(4096), 256, 0, stream>>>(mlp_W + (long long)i * 1048576, mlp2, 1024, 1024, 1024);
    k_fsplit<<<dim3(384), 256, 0, stream>>>(sK_W + (long long)i * 98304, sK2, 1024, 96, 1024);
    k_fsplit<<<dim3(4096), 256, 0, stream>>>(tV_W + (long long)i * 1048576, tV2, 1024, 1024, 1024);
    k_fsplit<<<dim3(384), 256, 0, stream>>>(sV_W + (long long)i * 98304, sV2, 1024, 96, 1024);
    if (i == 1) k_fsplit<<<dim3(512), 256, 0, stream>>>(lin_W, lin2, 96, 1024, 128);
    k_cp4<<<dim3(1), 256, 0, stream>>>((const float4*)(tQ_b + i * 1024), (float4*)bias2, 256);
    k_cp4<<<dim3(1), 256, 0, stream>>>((const float4*)(tK_b + i * 1024), (float4*)(bias2 + 1024), 256);

    for (int c = 0; c < 8; c++) {
      uint16_t* Hpc = Hp + (long long)c * 4096 * 2048;
      uint16_t* Xpc = Xp + (long long)c * 4096 * 192;
      // --- temporal (causal) ---
      k_gemmX<0,1,1,0,0,0,0,0, 2,2,1><<<dim3(32, 8, 2), 256, 0, stream>>>(
          Hpc, 2048, 0, 1024, tQ2, 2048, 2097152, 1024, nullptr, 0, 0,
          Qc, 2048, 8388608, 1024, nullptr, 0, 0, 0, bias2, 1024, 0.f, 32, 1024);
      k_gemmX<0,0,2,0,0,0,1,0, 2,2,1><<<dim3(8, 32, 1), 256, 0, stream>>>(
          tV2, 2048, 0, 1024, Hpc, 2048, 0, 1024, nullptr, 0, 0, Vc, 0, 0, 0,
          nullptr, 0, 0, 0, tV_b + i * 1024, 0, 0.f, 32, 4096);
      k_gemmX<1,0,0,0,0,1,0,0, 2,2,1><<<dim3(4, 4, 8), 256, 0, stream>>>(
          Qc, 2048, 1048576, 1024, Kc, 2048, 1048576, 1024, scr, 512, 262144,
          nullptr, 0, 0, 0, nullptr, 0, 0, 0, nullptr, 0, 0.03125f, 32, 512);
      k_softmax<<<dim3(1024), 256, 0, stream>>>(scr, 1);
      k_gemmX<0,1,0,1,0,0,0,0, 2,2,1><<<dim3(4, 8, 8), 256, 0, stream>>>(
          (const uint16_t*)scr, 1024, 524288, 512, Vc, 1024, 1048576, 512,
          nullptr, 0, 0, Hpc, 2048, 1048576, 1024, nullptr, 0, 0, 0, nullptr, 0, 0.f, 16, 1024);
      // --- spatial (K/V from X, no mask) ---
      k_gemmX<0,1,1,0,0,0,0,0, 2,2,1><<<dim3(32, 8, 1), 256, 0, stream>>>(
          Hpc, 2048, 0, 1024, sQ2, 2048, 0, 1024, nullptr, 0, 0,
          Qc, 2048, 0, 1024, nullptr, 0, 0, 0, sQ_b + i * 1024, 0, 0.f, 32, 1024);
      k_gemmX<0,1,1,0,0,0,0,0, 2,2,1><<<dim3(32, 8, 1), 256, 0, stream>>>(
          Xpc, 192, 0, 96, sK2, 192, 0, 96, nullptr, 0, 0,
          Kc, 2048, 0, 1024, nullptr, 0, 0, 0, sK_b + i * 1024, 0, 0.f, 3, 1024);
      k_gemmX<0,0,2,0,0,0,1,0, 2,2,1><<<dim3(8, 32, 1), 256, 0, stream>>>(
          sV2, 192, 0, 96, Xpc, 192, 0, 96, nullptr, 0, 0, Vc, 0, 0, 0,
          nullptr, 0, 0, 0, sV_b + i * 1024, 0, 0.f, 3, 4096);
      k_gemmX<1,0,0,0,0,1,0,0, 2,2,1><<<dim3(4, 4, 8), 256, 0, stream>>>(
          Qc, 2048, 1048576, 1024, Kc, 2048, 1048576, 1024, scr, 512, 262144,
          nullptr, 0, 0, 0, nullptr, 0, 0, 0, nullptr, 0, 0.03125f, 32, 512);
      k_softmax<<<dim3(1024), 256, 0, stream>>>(scr, 0);
      // PV2: pair residual into Hp AND snapshot into Qc (MLP input; Q is dead)
      k_gemmX<0,1,0,1,0,0,0,1, 2,2,1><<<dim3(4, 8, 8), 256, 0, stream>>>(
          (const uint16_t*)scr, 1024, 524288, 512, Vc, 1024, 1048576, 512,
          nullptr, 0, 0, Hpc, 2048, 1048576, 1024, Qc, 2048, 1048576, 1024, nullptr, 0, 0.f, 16, 1024);
      // --- MLP: reads Qc snapshot, writes Hp (no alias) ---
      k_gemmX<0,1,1,0,1,0,0,0, 2,2,1><<<dim3(32, 8, 1), 256, 0, stream>>>(
          Qc, 2048, 0, 1024, mlp2, 2048, 0, 1024, nullptr, 0, 0,
          Hpc, 2048, 0, 1024, nullptr, 0, 0, 0, mlp_b + i * 1024, 0, 0.f, 32, 1024);
    }
  }
  // ---- head: out = H @ lin_W^T + lin_b — one launch over all rows
  k_gemmX<1,0,1,0,0,0,0,0, 2,2,1><<<dim3(256, 1, 1), 256, 0, stream>>>(
      Hp, 2048, 0, 1024, lin2, 2048, 0, 1024, (float*)d_out, 96, 0,
      nullptr, 0, 0, 0, nullptr, 0, 0, 0, lin_b, 0, 0.f, 32, 96);
}

// Round 13
// 25772.552 us; speedup vs baseline: 1.4162x; 1.0288x over previous
//
#include <hip/hip_runtime.h>
#include <stdint.h>

// Decoder_71880572665909 : GRU scan (T=511) + 2 x (causal self-attn + cross-attn + MLP) + linear head
// B=64, S=512, HID=1024, POSE=96, L=2.
// Round-13: add 64x128 GEMM tile mode (M64) for all phase-2 launches that were at <=1 block/CU
// (sQ/MLP/V^T/PV/QK^T/head). Grids double, LDS 32->24KB, acc 64->32 VGPR -> 3-4 blocks/CU
// resident -> barrier drains overlap. Numerics unchanged from r12 (absmax 0.375). ~218 MiB.

typedef __attribute__((ext_vector_type(8))) short short8;
typedef __attribute__((ext_vector_type(4))) float f32x4;

__device__ __forceinline__ uint16_t f2bf(float f) {
  uint32_t u = __float_as_uint(f);
  uint32_t r = u + 0x7FFFu + ((u >> 16) & 1u);
  return (uint16_t)(r >> 16);
}
__device__ __forceinline__ float bf2f(uint16_t h) {
  return __uint_as_float(((uint32_t)h) << 16);
}
__device__ __forceinline__ float sigm(float x) { return 1.f / (1.f + __expf(-x)); }
__device__ __forceinline__ float tanh_(float x) { return 2.f / (1.f + __expf(-2.f * x)) - 1.f; }
__device__ __forceinline__ short8 ld8(const uint16_t* p) { return *(const short8*)p; }

__device__ __forceinline__ void stage16(const void* g, void* lds_base_uniform) {
  __builtin_amdgcn_global_load_lds((const __attribute__((address_space(1))) void*)g,
                                   (__attribute__((address_space(3))) void*)lds_base_uniform, 16, 0, 0);
}
__device__ __forceinline__ void tri_store(uint16_t* p, long long o0, long long o1, long long o2, float v) {
  uint16_t hi = f2bf(v);
  float r = v - bf2f(hi);
  uint16_t mid = f2bf(r);
  p[o0] = hi; p[o1] = mid; p[o2] = f2bf(r - bf2f(mid));
}
__device__ __forceinline__ void pair_store(uint16_t* p, long long o0, long long o1, float v) {
  uint16_t hi = f2bf(v);
  p[o0] = hi; p[o1] = f2bf(v - bf2f(hi));
}

// ---------------------------------------------------------------- prep / utility kernels

__global__ __launch_bounds__(256) void k_fill(float* __restrict__ o, int n, float v) {
  int i = blockIdx.x * 256 + threadIdx.x;
  if (i < n) o[i] = v;
}

__global__ __launch_bounds__(256) void k_cp4(const float4* __restrict__ s, float4* __restrict__ d, int n4) {
  int i = blockIdx.x * 256 + threadIdx.x;
  if (i < n4) d[i] = s[i];
}

// in-place f32 row [1024] -> pair bf16 row [2048] (hi 1024 | lo 1024), same bytes. wave-per-row.
__global__ __launch_bounds__(512) void k_cvtH(float* __restrict__ Hf) {
  int r = blockIdx.x * 8 + (threadIdx.x >> 6);
  int l = threadIdx.x & 63;
  float* row = Hf + (long long)r * 1024;
  float v[16];
#pragma unroll
  for (int t = 0; t < 16; t++) v[t] = row[l + 64 * t];
  __syncthreads();
  uint16_t* o = (uint16_t*)row;
#pragma unroll
  for (int t = 0; t < 16; t++) {
    int j = l + 64 * t;
    uint16_t hi = f2bf(v[t]);
    o[j] = hi; o[1024 + j] = f2bf(v[t] - bf2f(hi));
  }
}

// in-place f32 row [96] -> pair bf16 row [192], same bytes. wave-per-row.
__global__ __launch_bounds__(512) void k_cvtX(float* __restrict__ Xf) {
  int r = blockIdx.x * 8 + (threadIdx.x >> 6);
  int l = threadIdx.x & 63;
  float* row = Xf + (long long)r * 96;
  float v0 = row[l];
  float v1 = (l < 32) ? row[64 + l] : 0.f;
  __syncthreads();
  uint16_t* o = (uint16_t*)row;
  uint16_t h0 = f2bf(v0);
  o[l] = h0; o[96 + l] = f2bf(v0 - bf2f(h0));
  if (l < 32) {
    uint16_t h1 = f2bf(v1);
    o[64 + l] = h1; o[160 + l] = f2bf(v1 - bf2f(h1));
  }
}

// f32 W [N][K] -> pair [Npad][2K]
__global__ __launch_bounds__(256) void k_fsplit(const float* __restrict__ s, uint16_t* __restrict__ d,
                                                int N, int K, int Npad) {
  int id = blockIdx.x * 256 + threadIdx.x;
  if (id >= Npad * K) return;
  int n = id / K, k = id % K;
  float w = (n < N) ? s[(long long)n * K + k] : 0.f;
  pair_store(d, (long long)n * 2 * K + k, (long long)n * 2 * K + K + k, w);
}

// x_{-1} = x0 - h0 @ tp_W^T - tp_b  (triple out; feeds step-0 gi)
__global__ __launch_bounds__(256) void k_xm1(const float* __restrict__ h, const float* __restrict__ gt,
                                             const float* __restrict__ tp_W, const float* __restrict__ tp_b,
                                             uint16_t* __restrict__ Xm1) {
  int id = blockIdx.x * 256 + threadIdx.x;
  if (id >= 64 * 96) return;
  int b = id / 96, c = id % 96;
  float s = gt[(long long)b * 512 * 96 + c] - tp_b[c];
  const float* hr = &h[(long long)b * 1024];
  const float* wr = &tp_W[(long long)c * 1024];
  for (int k = 0; k < 1024; k++) s -= hr[k] * wr[k];
  tri_store(Xm1, b * 288 + c, b * 288 + 96 + c, b * 288 + 192 + c, s);
}

// gates pack: K=1120 x N=6144 fragment order [384 tiles][35 ks][64][8], hi+mid planes
__global__ __launch_bounds__(256) void k_pack(const float* __restrict__ W_hh, const float* __restrict__ W_ih,
                                              const float* __restrict__ tp_W,
                                              uint16_t* __restrict__ B0, uint16_t* __restrict__ B1) {
  int id = blockIdx.x * 256 + threadIdx.x;
  if (id >= 384 * 35 * 64) return;
  int tile = id / 2240, rem = id % 2240;
  int ks = rem >> 6, l = rem & 63;
  int n = tile * 16 + (l & 15);
  int kb = ks * 32 + (l >> 4) * 8;
  short8 v0, v1;
#pragma unroll
  for (int i = 0; i < 8; i++) {
    int k = kb + i;
    float m = 0.f;
    if (n < 3072) {
      m = (k < 1024) ? W_hh[(long long)n * 1024 + k] : 0.f;
    } else {
      int j = n - 3072;
      if (k < 1024) {
        float s = 0.f;
        for (int q = 0; q < 96; q++) s += tp_W[q * 1024 + k] * W_ih[(long long)j * 96 + q];
        m = s;
      } else {
        m = W_ih[(long long)j * 96 + (k - 1024)];
      }
    }
    uint16_t hi = f2bf(m);
    v0[i] = (short)hi; v1[i] = (short)f2bf(m - bf2f(hi));
  }
  *(short8*)&B0[(long long)id * 8] = v0;
  *(short8*)&B1[(long long)id * 8] = v1;
}

// x-update pack: tp_W [6 tiles][32 ks][64][8], triple planes (plane stride 98304 u16)
__global__ __launch_bounds__(256) void k_packx(const float* __restrict__ tp_W, uint16_t* __restrict__ Bx) {
  int id = blockIdx.x * 256 + threadIdx.x;
  if (id >= 6 * 32 * 64) return;
  int tile = id / 2048, rem = id % 2048;
  int ks = rem >> 6, l = rem & 63;
  int c = tile * 16 + (l & 15);
  int lg = l >> 4;
  short8 v0, v1, v2;
#pragma unroll
  for (int i = 0; i < 8; i++) {
    int k = ks * 32 + lg * 8 + i;
    float w = tp_W[(long long)c * 1024 + k];
    uint16_t hi = f2bf(w);
    float r = w - bf2f(hi);
    uint16_t mid = f2bf(r);
    v0[i] = (short)hi; v1[i] = (short)mid; v2[i] = (short)f2bf(r - bf2f(mid));
  }
  *(short8*)&Bx[(long long)id * 8] = v0;
  *(short8*)&Bx[98304 + (long long)id * 8] = v1;
  *(short8*)&Bx[196608 + (long long)id * 8] = v2;
}

__global__ __launch_bounds__(256) void k_c6(const float* __restrict__ b_ih, const float* __restrict__ b_hh,
                                            const float* __restrict__ W_ih, const float* __restrict__ tp_b,
                                            float* __restrict__ c6m) {
  int n = blockIdx.x * 256 + threadIdx.x;
  if (n >= 6240) return;
  float m;
  if (n < 3072) { m = b_hh[n]; }
  else if (n < 6144) {
    int j = n - 3072;
    float s = 0.f;
    for (int q = 0; q < 96; q++) s += W_ih[(long long)j * 96 + q] * tp_b[q];
    m = b_ih[j] + s;
  } else { m = tp_b[n - 6144]; }
  c6m[n] = m;
}

__global__ __launch_bounds__(256) void k_init(const float* __restrict__ h, const float* __restrict__ gt,
                                              float* Hf, uint16_t* Hr, float* Xf, uint16_t* Xr) {
  int id = blockIdx.x * 256 + threadIdx.x;
  if (id < 65536) {
    int b = id >> 10, d = id & 1023;
    float v = h[id];
    Hf[((long long)b * 512) * 1024 + d] = v;
    tri_store(Hr, b * 3072 + d, b * 3072 + 1024 + d, b * 3072 + 2048 + d, v);
  } else {
    int r2 = id - 65536;
    if (r2 < 6144) {
      int b = r2 / 96, c = r2 % 96;
      float v = gt[(long long)b * 512 * 96 + c];
      Xf[((long long)b * 512) * 96 + c] = v;
      tri_store(Xr, b * 288 + c, b * 288 + 96 + c, b * 288 + 192 + c, v);
    }
  }
}

// ---------------------------------------------------------------- GRU step (one launch per step)
// grid 66: blocks 0..63 gates (16 j-cols x 6 strips), blocks 64,65 x-update (48 cols each).
__global__ __launch_bounds__(512) void k_gru(const uint16_t* __restrict__ B0, const uint16_t* __restrict__ B1,
                                             const uint16_t* __restrict__ Bx, const float* __restrict__ c6,
                                             float* Hf, uint16_t* Hr, float* Xf, uint16_t* Xr,
                                             const uint16_t* __restrict__ Xm1, int p) {
  int tid = threadIdx.x, w = tid >> 6, l = tid & 63, lr = l & 15, lg = l >> 4;
  int blk = blockIdx.x;
  const uint16_t* Hcur = Hr + (p & 1) * 196608;
  uint16_t* Hnxt = Hr + ((p + 1) & 1) * 196608;
  uint16_t* Xw = Xr + (p & 1) * 18432;
  const uint16_t* Xg = (p == 0) ? Xm1 : (Xr + ((p - 1) & 1) * 18432);
  __shared__ float lds[4 * 6144];

  if (blk >= 64) {  // x-update: x_p = x_{p-1} + h_p @ tpW^T + tp_b ; X6 precision
    if (p < 1) return;
    int xb = blk - 64;
    if (w < 6) {
      int tl = xb * 3 + (w >> 1);
      int kh = w & 1;
      f32x4 ac[4] = {};
      for (int ks = kh * 16; ks < kh * 16 + 16; ks++) {
        short8 a0[4], a1[4], a2[4];
        int k0 = ks * 32 + lg * 8;
#pragma unroll
        for (int rt = 0; rt < 4; rt++) {
          int hb = (rt * 16 + lr) * 3072;
          a0[rt] = ld8(&Hcur[hb + k0]);
          a1[rt] = ld8(&Hcur[hb + 1024 + k0]);
          a2[rt] = ld8(&Hcur[hb + 2048 + k0]);
        }
        long long bo = (((long long)tl * 32 + ks) * 64 + l) * 8;
        short8 b0 = ld8(&Bx[bo]);
        short8 b1 = ld8(&Bx[98304 + bo]);
        short8 b2 = ld8(&Bx[196608 + bo]);
#pragma unroll
        for (int rt = 0; rt < 4; rt++) {
          ac[rt] = __builtin_amdgcn_mfma_f32_16x16x32_bf16(a0[rt], b0, ac[rt], 0, 0, 0);
          ac[rt] = __builtin_amdgcn_mfma_f32_16x16x32_bf16(a0[rt], b1, ac[rt], 0, 0, 0);
          ac[rt] = __builtin_amdgcn_mfma_f32_16x16x32_bf16(a1[rt], b0, ac[rt], 0, 0, 0);
          ac[rt] = __builtin_amdgcn_mfma_f32_16x16x32_bf16(a1[rt], b1, ac[rt], 0, 0, 0);
          ac[rt] = __builtin_amdgcn_mfma_f32_16x16x32_bf16(a0[rt], b2, ac[rt], 0, 0, 0);
          ac[rt] = __builtin_amdgcn_mfma_f32_16x16x32_bf16(a2[rt], b0, ac[rt], 0, 0, 0);
        }
      }
#pragma unroll
      for (int rt = 0; rt < 4; rt++)
#pragma unroll
        for (int rg = 0; rg < 4; rg++)
          lds[w * 1024 + (rt * 16 + 4 * lg + rg) * 16 + lr] = ac[rt][rg];
    }
    __syncthreads();
    for (int idx = tid; idx < 3072; idx += 512) {
      int ti = idx >> 10, rem = idx & 1023;
      int row = rem >> 4, cl = rem & 15;
      float v = lds[(2 * ti) * 1024 + row * 16 + cl] + lds[(2 * ti + 1) * 1024 + row * 16 + cl];
      int c = (xb * 3 + ti) * 16 + cl;
      float xold = Xf[((long long)row * 512 + p - 1) * 96 + c];
      float xv = v + c6[6144 + c] + xold;
      Xf[((long long)row * 512 + p) * 96 + c] = xv;
      tri_store(Xw, row * 288 + c, row * 288 + 96 + c, row * 288 + 192 + c, xv);
    }
    return;
  }

  if (p >= 511) return;
  // gates: j in [blk*16, +16); tiles s*64+blk for s=0..5. 8 waves split K(35 ks). X3 pair-weights.
  int ks0 = (w * 35) >> 3, ks1 = ((w + 1) * 35) >> 3;
  f32x4 acc[6][4] = {};
  for (int ks = ks0; ks < ks1; ks++) {
    short8 a0[4], a1[4];
    if (ks < 32) {
      int k0 = ks * 32 + lg * 8;
#pragma unroll
      for (int rt = 0; rt < 4; rt++) {
        int hb = (rt * 16 + lr) * 3072;
        a0[rt] = ld8(&Hcur[hb + k0]);
        a1[rt] = ld8(&Hcur[hb + 1024 + k0]);
      }
    } else {
      int k0 = (ks - 32) * 32 + lg * 8;
#pragma unroll
      for (int rt = 0; rt < 4; rt++) {
        int xb2 = (rt * 16 + lr) * 288;
        a0[rt] = ld8(&Xg[xb2 + k0]);
        a1[rt] = ld8(&Xg[xb2 + 96 + k0]);
      }
    }
#pragma unroll
    for (int t = 0; t < 6; t++) {
      long long bo = (((long long)(t * 64 + blk)) * 35 + ks) * 64 * 8 + (long long)l * 8;
      short8 b0 = ld8(&B0[bo]);
      short8 b1 = ld8(&B1[bo]);
#pragma unroll
      for (int rt = 0; rt < 4; rt++) {
        acc[t][rt] = __builtin_amdgcn_mfma_f32_16x16x32_bf16(a0[rt], b0, acc[t][rt], 0, 0, 0);
        acc[t][rt] = __builtin_amdgcn_mfma_f32_16x16x32_bf16(a0[rt], b1, acc[t][rt], 0, 0, 0);
        acc[t][rt] = __builtin_amdgcn_mfma_f32_16x16x32_bf16(a1[rt], b0, acc[t][rt], 0, 0, 0);
      }
    }
  }
  int slab = w & 3;
  if (w < 4) {
#pragma unroll
    for (int t = 0; t < 6; t++)
#pragma unroll
      for (int rt = 0; rt < 4; rt++)
#pragma unroll
        for (int rg = 0; rg < 4; rg++)
          lds[slab * 6144 + (rt * 16 + 4 * lg + rg) * 96 + t * 16 + lr] = acc[t][rt][rg];
  }
  __syncthreads();
  if (w >= 4) {
#pragma unroll
    for (int t = 0; t < 6; t++)
#pragma unroll
      for (int rt = 0; rt < 4; rt++)
#pragma unroll
        for (int rg = 0; rg < 4; rg++)
          lds[slab * 6144 + (rt * 16 + 4 * lg + rg) * 96 + t * 16 + lr] += acc[t][rt][rg];
  }
  __syncthreads();
  for (int idx = tid; idx < 6144; idx += 512)
    lds[idx] = lds[idx] + lds[6144 + idx] + lds[12288 + idx] + lds[18432 + idx];
  __syncthreads();
  for (int item = tid; item < 1024; item += 512) {
    int b = item >> 4, jj = item & 15;
    int j = blk * 16 + jj;
    const float* row = &lds[b * 96];
    float hr = row[jj]       + c6[j];
    float hz = row[16 + jj]  + c6[1024 + j];
    float hnn = row[32 + jj] + c6[2048 + j];
    float ir = row[48 + jj]  + c6[3072 + j];
    float iz = row[64 + jj]  + c6[4096 + j];
    float inn = row[80 + jj] + c6[5120 + j];
    float hp = Hf[((long long)b * 512 + p) * 1024 + j];
    float r = sigm(ir + hr), z = sigm(iz + hz);
    float nn = tanh_(inn + r * hnn);
    float hv = (1.f - z) * nn + z * hp;
    Hf[((long long)b * 512 + p + 1) * 1024 + j] = hv;
    tri_store(Hnxt, b * 3072 + j, b * 3072 + 1024 + j, b * 3072 + 2048 + j, hv);
  }
}

// ---------------------------------------------------------------- generic multi-word GEMM
// A row-major [M][lda], words at w*koffA. B = B^T row-major [N][ldb], words at w*koffB.
// Products a_i*b_j with i+j <= CUT. M64=1: 64x128 tile (4 waves of 64rows x 32cols), else 128x128.
template <int WF32, int WPAIR, int BIAS, int RESIDP, int LEAKY, int SCALE, int VLAY, int SNAP,
          int AW, int BW, int CUT, int M64>
__global__ __launch_bounds__(256) void k_gemmX(const uint16_t* __restrict__ A, int lda, long long bsA, int koffA,
                                               const uint16_t* __restrict__ B, int ldb, long long bsB, int koffB,
                                               float* __restrict__ C, int ldc, long long bsC,
                                               uint16_t* __restrict__ Cb, int ldcb, long long bsCb, int pairoff,
                                               uint16_t* __restrict__ Cb2, int ldcb2, long long bsCb2, int pairoff2,
                                               const float* __restrict__ bias, long long bsBias,
                                               float scale, int nk, int Nvalid) {
  constexpr int MROWS = M64 ? 64 : 128;
  constexpr int ABYT = M64 ? 4096 : 8192;
  constexpr int NF = M64 ? 2 : 4;
  int tid = threadIdx.x, w = tid >> 6, l = tid & 63, lr = l & 15, lg = l >> 4;
  long long bz = blockIdx.z;
  int brow = blockIdx.x * MROWS, bcol = blockIdx.y * 128;
  const uint16_t* Ab = A + bz * bsA;
  const uint16_t* Bb = B + bz * bsB;
  const float* biasz = bias ? bias + bz * bsBias : bias;
  __shared__ uint16_t sm[(AW * ABYT + BW * 8192) / 2];
  char* L = (char*)sm;
  f32x4 acc[4][NF] = {};
  int wr = M64 ? 0 : (w >> 1) * 64;
  int wc = M64 ? (w * 32) : ((w & 1) * 64);
  int srow = tid >> 2, skoff = (tid & 3) * 8;
  for (int ks = 0; ks < nk; ks++) {
    __syncthreads();
    int k0 = ks * 32 + skoff;
#pragma unroll
    for (int aw = 0; aw < AW; aw++) {
      stage16(Ab + (long long)(brow + srow) * lda + aw * koffA + k0,        L + aw * ABYT + w * 1024);
      if (!M64)
        stage16(Ab + (long long)(brow + 64 + srow) * lda + aw * koffA + k0, L + aw * ABYT + 4096 + w * 1024);
    }
#pragma unroll
    for (int bw = 0; bw < BW; bw++) {
      stage16(Bb + (long long)(bcol + srow) * ldb + bw * koffB + k0,      L + AW * ABYT + bw * 8192 + w * 1024);
      stage16(Bb + (long long)(bcol + 64 + srow) * ldb + bw * koffB + k0, L + AW * ABYT + bw * 8192 + 4096 + w * 1024);
    }
    __syncthreads();
    short8 af[AW][4], bf[BW][NF];
#pragma unroll
    for (int aw = 0; aw < AW; aw++)
#pragma unroll
      for (int mi = 0; mi < 4; mi++)
        af[aw][mi] = *(short8*)(L + aw * ABYT + ((wr + mi * 16 + lr) * 32 + lg * 8) * 2);
#pragma unroll
    for (int bw = 0; bw < BW; bw++)
#pragma unroll
      for (int ni = 0; ni < NF; ni++)
        bf[bw][ni] = *(short8*)(L + AW * ABYT + bw * 8192 + ((wc + ni * 16 + lr) * 32 + lg * 8) * 2);
#pragma unroll
    for (int mi = 0; mi < 4; mi++)
#pragma unroll
      for (int ni = 0; ni < NF; ni++)
#pragma unroll
        for (int iw = 0; iw < AW; iw++)
#pragma unroll
          for (int jw = 0; jw < BW; jw++)
            if (iw + jw <= CUT)
              acc[mi][ni] = __builtin_amdgcn_mfma_f32_16x16x32_bf16(af[iw][mi], bf[jw][ni], acc[mi][ni], 0, 0, 0);
  }
#pragma unroll
  for (int mi = 0; mi < 4; mi++) {
#pragma unroll
    for (int ni = 0; ni < NF; ni++) {
      int row0 = brow + wr + mi * 16 + 4 * lg;
      int col = bcol + wc + ni * 16 + lr;
      if (col < Nvalid) {
#pragma unroll
        for (int rg = 0; rg < 4; rg++) {
          float v = acc[mi][ni][rg];
          if (SCALE) v *= scale;
          if (BIAS == 1) v += biasz[col];
          if (BIAS == 2) v += biasz[row0 + rg];
          long long cbi = 0;
          if (WPAIR || RESIDP) cbi = bz * bsCb + (long long)(row0 + rg) * ldcb + col;
          if (RESIDP) v += bf2f(Cb[cbi]) + bf2f(Cb[cbi + pairoff]);
          if (LEAKY) v = (v > 0.f) ? v : 0.01f * v;
          if (WF32) C[bz * bsC + (long long)(row0 + rg) * ldc + col] = v;
          if (WPAIR) pair_store(Cb, cbi, cbi + pairoff, v);
          if (SNAP) {
            long long c2 = bz * bsCb2 + (long long)(row0 + rg) * ldcb2 + col;
            pair_store(Cb2, c2, c2 + pairoff2, v);
          }
          if (VLAY) {  // V^T pair layout per 512-batch: [bz2][d 1024][hi 512 | lo 512]
            int bz2 = col >> 9, t = col & 511;
            long long vi = (long long)bz2 * 1048576 + (long long)(row0 + rg) * 1024 + t;
            pair_store(Cb, vi, vi + 512, v);
          }
        }
      }
    }
  }
}

// ---------------------------------------------------------------- softmax (rows of 512), P pair overlays scr
__global__ __launch_bounds__(256) void k_softmax(float* __restrict__ sc, int causal) {
  int r = blockIdx.x * 4 + (threadIdx.x >> 6);
  int l = threadIdx.x & 63;
  int s = r & 511;
  long long base = (long long)r * 512;
  int t0 = l * 8;
  float4 p0 = *(const float4*)&sc[base + t0];
  float4 p1 = *(const float4*)&sc[base + t0 + 4];
  float v[8] = {p0.x, p0.y, p0.z, p0.w, p1.x, p1.y, p1.z, p1.w};
  float m = -3.0e38f;
#pragma unroll
  for (int i = 0; i < 8; i++) {
    bool ok = (!causal) || (t0 + i <= s);
    if (ok) m = fmaxf(m, v[i]);
  }
#pragma unroll
  for (int o = 32; o > 0; o >>= 1) m = fmaxf(m, __shfl_xor(m, o));
  float e[8];
  float sum = 0.f;
#pragma unroll
  for (int i = 0; i < 8; i++) {
    bool ok = (!causal) || (t0 + i <= s);
    e[i] = ok ? __expf(v[i] - m) : 0.f;
    sum += e[i];
  }
#pragma unroll
  for (int o = 32; o > 0; o >>= 1) sum += __shfl_xor(sum, o);
  float inv = 1.f / sum;
  short8 oh, ol;
#pragma unroll
  for (int i = 0; i < 8; i++) {
    float p = e[i] * inv;
    uint16_t hi = f2bf(p);
    oh[i] = hi; ol[i] = (short)f2bf(p - bf2f(hi));
  }
  uint16_t* P = (uint16_t*)sc;   // single wave owns the row: loads done before stores
  long long pb = (long long)r * 1024;
  *(short8*)&P[pb + t0] = oh;
  *(short8*)&P[pb + 512 + t0] = ol;
}

// ---------------------------------------------------------------- host
extern "C" void kernel_launch(void* const* d_in, const int* in_sizes, int n_in,
                              void* d_out, int out_size, void* d_ws, size_t ws_size,
                              hipStream_t stream) {
  const float* h    = (const float*)d_in[0];
  const float* gt   = (const float*)d_in[1];
  const float* W_ih = (const float*)d_in[3];
  const float* W_hh = (const float*)d_in[4];
  const float* b_ih = (const float*)d_in[5];
  const float* b_hh = (const float*)d_in[6];
  const float* tp_W = (const float*)d_in[7];
  const float* tp_b = (const float*)d_in[8];
  const float* tQ_W = (const float*)d_in[9];
  const float* tQ_b = (const float*)d_in[10];
  const float* tK_W = (const float*)d_in[11];
  const float* tK_b = (const float*)d_in[12];
  const float* tV_W = (const float*)d_in[13];
  const float* tV_b = (const float*)d_in[14];
  const float* sQ_W = (const float*)d_in[15];
  const float* sQ_b = (const float*)d_in[16];
  const float* sK_W = (const float*)d_in[17];
  const float* sK_b = (const float*)d_in[18];
  const float* sV_W = (const float*)d_in[19];
  const float* sV_b = (const float*)d_in[20];
  const float* mlp_W= (const float*)d_in[21];
  const float* mlp_b= (const float*)d_in[22];
  const float* lin_W= (const float*)d_in[23];
  const float* lin_b= (const float*)d_in[24];
  (void)in_sizes; (void)n_in;

  char* wsb = (char*)d_ws;
  size_t off = 0;
  auto carve = [&](size_t bytes) -> void* {
    void* p = wsb + off;
    off += (bytes + 255) & ~(size_t)255;
    return p;
  };
  // Wreg: phase-1 GRU packs (28.1MB) / phase-2 pair weights (21.25MB) + scr (8MB)
  char* Wreg = (char*)carve(30670848);
  uint16_t* B0 = (uint16_t*)Wreg;
  uint16_t* B1 = (uint16_t*)(Wreg + 13762560);
  uint16_t* Bx = (uint16_t*)(Wreg + 27525120);
  uint16_t* tQ2 = (uint16_t*)(Wreg);                    // pair; tK2 adjacent at +4194304 B
  uint16_t* sQ2 = (uint16_t*)(Wreg + 8388608);
  uint16_t* mlp2= (uint16_t*)(Wreg + 12582912);
  uint16_t* sK2 = (uint16_t*)(Wreg + 16777216);
  uint16_t* tV2 = (uint16_t*)(Wreg + 17170432);
  uint16_t* sV2 = (uint16_t*)(Wreg + 21364736);
  uint16_t* lin2= (uint16_t*)(Wreg + 21757952);
  float* scr    = (float*)(Wreg + 22282240);            // 8 MB chunk scores; P pair overlays
  float* c6m    = (float*)carve(6240 * 4);
  float* Hf     = (float*)carve(32768LL * 1024 * 4);    // 128MB f32 H (phase 1) -> pair Hp (phase 2)
  float* Xf     = (float*)carve(32768LL * 96 * 4);      // 12MB  f32 X (phase 1) -> pair Xp (phase 2)
  uint16_t* Hr  = (uint16_t*)carve(2 * 64 * 3072 * 2);  // rolling h triple (ping-pong)
  uint16_t* Xr  = (uint16_t*)carve(2 * 64 * 288 * 2);   // rolling x triple
  uint16_t* Xm1 = (uint16_t*)carve(64 * 288 * 2);
  float* bias2  = (float*)carve(2048 * 4);              // merged tQ_b|tK_b
  uint16_t* Qc  = (uint16_t*)carve(4096LL * 2048 * 2);  // 16MB chunk Q pair (Kc adjacent for z=2)
  uint16_t* Kc  = (uint16_t*)carve(4096LL * 2048 * 2);  // 16MB chunk K pair
  uint16_t* Vc  = (uint16_t*)carve(8LL * 1024 * 1024 * 2); // 16MB chunk V^T pair [8][1024][1024]
  size_t need = off;  // ~218 MiB
  if (ws_size < need) {
    k_fill<<<dim3((out_size + 255) / 256), 256, 0, stream>>>((float*)d_out, out_size,
                                                             50000.0f + (float)(ws_size >> 20));
    return;
  }
  uint16_t* Hp = (uint16_t*)Hf;   // phase-2 pair view (in-place converted)
  uint16_t* Xp = (uint16_t*)Xf;

  // ---- phase 1 prep
  k_pack<<<dim3(3360), 256, 0, stream>>>(W_hh, W_ih, tp_W, B0, B1);
  k_packx<<<dim3(48), 256, 0, stream>>>(tp_W, Bx);
  k_c6<<<dim3(25), 256, 0, stream>>>(b_ih, b_hh, W_ih, tp_b, c6m);
  k_init<<<dim3(280), 256, 0, stream>>>(h, gt, Hf, Hr, Xf, Xr);
  k_xm1<<<dim3(24), 256, 0, stream>>>(h, gt, tp_W, tp_b, Xm1);

  // ---- phase 1: GRU scan (step p: gates -> h_{p+1}; x-update -> x_p)
  for (int p = 0; p < 512; p++)
    k_gru<<<dim3(66), dim3(512), 0, stream>>>(B0, B1, Bx, c6m, Hf, Hr, Xf, Xr, Xm1, p);

  // ---- convert trajectories in place: f32 -> pair bf16 (same bytes)
  k_cvtH<<<dim3(4096), 512, 0, stream>>>(Hf);
  k_cvtX<<<dim3(4096), 512, 0, stream>>>(Xf);

  // ---- phase 2: 8 chunks x 4096 rows (8 batches each), all GEMMs X3 pair
  for (int i = 0; i < 2; i++) {
    k_fsplit<<<dim3(4096), 256, 0, stream>>>(tQ_W + (long long)i * 1048576, tQ2, 1024, 1024, 1024);
    k_fsplit<<<dim3(4096), 256, 0, stream>>>(tK_W + (long long)i * 1048576, tQ2 + 2097152, 1024, 1024, 1024);
    k_fsplit<<<dim3(4096), 256, 0, stream>>>(sQ_W + (long long)i * 1048576, sQ2, 1024, 1024, 1024);
    k_fsplit<<<dim3(4096), 256, 0, stream>>>(mlp_W + (long long)i * 1048576, mlp2, 1024, 1024, 1024);
    k_fsplit<<<dim3(384), 256, 0, stream>>>(sK_W + (long long)i * 98304, sK2, 1024, 96, 1024);
    k_fsplit<<<dim3(4096), 256, 0, stream>>>(tV_W + (long long)i * 1048576, tV2, 1024, 1024, 1024);
    k_fsplit<<<dim3(384), 256, 0, stream>>>(sV_W + (long long)i * 98304, sV2, 1024, 96, 1024);
    if (i == 1) k_fsplit<<<dim3(512), 256, 0, stream>>>(lin_W, lin2, 96, 1024, 128);
    k_cp4<<<dim3(1), 256, 0, stream>>>((const float4*)(tQ_b + i * 1024), (float4*)bias2, 256);
    k_cp4<<<dim3(1), 256, 0, stream>>>((const float4*)(tK_b + i * 1024), (float4*)(bias2 + 1024), 256);

    for (int c = 0; c < 8; c++) {
      uint16_t* Hpc = Hp + (long long)c * 4096 * 2048;
      uint16_t* Xpc = Xp + (long long)c * 4096 * 192;
      // --- temporal (causal) ---
      k_gemmX<0,1,1,0,0,0,0,0, 2,2,1,0><<<dim3(32, 8, 2), 256, 0, stream>>>(
          Hpc, 2048, 0, 1024, tQ2, 2048, 2097152, 1024, nullptr, 0, 0,
          Qc, 2048, 8388608, 1024, nullptr, 0, 0, 0, bias2, 1024, 0.f, 32, 1024);
      k_gemmX<0,0,2,0,0,0,1,0, 2,2,1,1><<<dim3(16, 32, 1), 256, 0, stream>>>(
          tV2, 2048, 0, 1024, Hpc, 2048, 0, 1024, nullptr, 0, 0, Vc, 0, 0, 0,
          nullptr, 0, 0, 0, tV_b + i * 1024, 0, 0.f, 32, 4096);
      k_gemmX<1,0,0,0,0,1,0,0, 2,2,1,1><<<dim3(8, 4, 8), 256, 0, stream>>>(
          Qc, 2048, 1048576, 1024, Kc, 2048, 1048576, 1024, scr, 512, 262144,
          nullptr, 0, 0, 0, nullptr, 0, 0, 0, nullptr, 0, 0.03125f, 32, 512);
      k_softmax<<<dim3(1024), 256, 0, stream>>>(scr, 1);
      k_gemmX<0,1,0,1,0,0,0,0, 2,2,1,1><<<dim3(8, 8, 8), 256, 0, stream>>>(
          (const uint16_t*)scr, 1024, 524288, 512, Vc, 1024, 1048576, 512,
          nullptr, 0, 0, Hpc, 2048, 1048576, 1024, nullptr, 0, 0, 0, nullptr, 0, 0.f, 16, 1024);
      // --- spatial (K/V from X, no mask) ---
      k_gemmX<0,1,1,0,0,0,0,0, 2,2,1,1><<<dim3(64, 8, 1), 256, 0, stream>>>(
          Hpc, 2048, 0, 1024, sQ2, 2048, 0, 1024, nullptr, 0, 0,
          Qc, 2048, 0, 1024, nullptr, 0, 0, 0, sQ_b + i * 1024, 0, 0.f, 32, 1024);
      k_gemmX<0,1,1,0,0,0,0,0, 2,2,1,1><<<dim3(64, 8, 1), 256, 0, stream>>>(
          Xpc, 192, 0, 96, sK2, 192, 0, 96, nullptr, 0, 0,
          Kc, 2048, 0, 1024, nullptr, 0, 0, 0, sK_b + i * 1024, 0, 0.f, 3, 1024);
      k_gemmX<0,0,2,0,0,0,1,0, 2,2,1,1><<<dim3(16, 32, 1), 256, 0, stream>>>(
          sV2, 192, 0, 96, Xpc, 192, 0, 96, nullptr, 0, 0, Vc, 0, 0, 0,
          nullptr, 0, 0, 0, sV_b + i * 1024, 0, 0.f, 3, 4096);
      k_gemmX<1,0,0,0,0,1,0,0, 2,2,1,1><<<dim3(8, 4, 8), 256, 0, stream>>>(
          Qc, 2048, 1048576, 1024, Kc, 2048, 1048576, 1024, scr, 512, 262144,
          nullptr, 0, 0, 0, nullptr, 0, 0, 0, nullptr, 0, 0.03125f, 32, 512);
      k_softmax<<<dim3(1024), 256, 0, stream>>>(scr, 0);
      // PV2: pair residual into Hp AND snapshot into Qc (MLP input; Q is dead)
      k_gemmX<0,1,0,1,0,0,0,1, 2,2,1,1><<<dim3(8, 8, 8), 256, 0, stream>>>(
          (const uint16_t*)scr, 1024, 524288, 512, Vc, 1024, 1048576, 512,
          nullptr, 0, 0, Hpc, 2048, 1048576, 1024, Qc, 2048, 1048576, 1024, nullptr, 0, 0.f, 16, 1024);
      // --- MLP: reads Qc snapshot, writes Hp (no alias) ---
      k_gemmX<0,1,1,0,1,0,0,0, 2,2,1,1><<<dim3(64, 8, 1), 256, 0, stream>>>(
          Qc, 2048, 0, 1024, mlp2, 2048, 0, 1024, nullptr, 0, 0,
          Hpc, 2048, 0, 1024, nullptr, 0, 0, 0, mlp_b + i * 1024, 0, 0.f, 32, 1024);
    }
  }
  // ---- head: out = H @ lin_W^T + lin_b — one launch over all rows
  k_gemmX<1,0,1,0,0,0,0,0, 2,2,1,1><<<dim3(512, 1, 1), 256, 0, stream>>>(
      Hp, 2048, 0, 1024, lin2, 2048, 0, 1024, (float*)d_out, 96, 0,
      nullptr, 0, 0, 0, nullptr, 0, 0, 0, lin_b, 0, 0.f, 32, 96);
}